// Round 4
// baseline (337647.388 us; speedup 1.0000x reference)
//
#include <hip/hip_runtime.h>
#include <math.h>

// Problem constants (fixed by setup_inputs)
#define TT  256   // scan steps
#define BB  32    // batch
#define EE  1024  // embed dim
#define MM  4096  // mlp dim
#define VV  4096  // vocab
#define BE  (BB*EE)      // 32768
#define NROWS (TT*BB)    // 8192
#define EPSF 1.1920929e-07f

// ======================= custom grid barrier =======================
// One fresh counter per barrier (no reset, no generation races). Counters
// zeroed by k_zero before the cooperative launch. Arrive-and-poll by
// thread 0 of each real block; agent-scope fences give cross-XCD visibility.
__device__ inline void gbar(unsigned* cnt, int idx, unsigned nblk) {
  __syncthreads();
  if (threadIdx.x == 0) {
    __builtin_amdgcn_fence(__ATOMIC_RELEASE, "agent");
    __hip_atomic_fetch_add(&cnt[idx], 1u, __ATOMIC_RELAXED,
                           __HIP_MEMORY_SCOPE_AGENT);
    while (__hip_atomic_load(&cnt[idx], __ATOMIC_RELAXED,
                             __HIP_MEMORY_SCOPE_AGENT) < nblk)
      __builtin_amdgcn_s_sleep(1);
    __builtin_amdgcn_fence(__ATOMIC_ACQUIRE, "agent");
  }
  __syncthreads();
}

// ======================= scan stages =======================
// vblk = virtual 256-thread block (2 per real 512-thread block).
// zpart layout: [b][m][8 k-slices]  (s-contiguous -> fc2 reads 2x float4)

struct ScanParams {
  const int* tokens;
  const float* embw;
  const float* bnw;
  const float* fc1w;
  const float* fc1b;
  const float* fc2w;
  const float* fc2b;
  const float* nw;
  const float* nxtw;
  const float* nxtb;
  float* inp_all;   // [TT][32][EE] (in d_out)
  float* s_all;     // [TT][32][EE] (in d_out)
  float* nxt_all;   // [TT][32][EE] (ws)
  float* zpart;     // [32][4096][8] (ws)
  float* hbuf;      // [32][EE]
  float* ssA;       // [TT][32]
  float* ssH;       // [TT][32]
  float* ssS;       // [TT][32]
  unsigned* cnt;    // barrier counters
};

// fc1-style partial GEMM with register-prefetch double buffering.
// zpart[b][m][ks] = sum_{e in slice ks} a[b][e]*scl[e]*W[m][e].
// 64 colgroups x 8 kslices = 512 vblks; tile 32 rows x 64 cols, 4x2/thread.
// ks-lead blocks (cgi==0) atomicAdd row sum-squares and optionally seed
// seedDst = a + seedBias (+ seedAdd) over their e-slice.
__device__ inline void stage_fc1(int vblk, int tid,
    const float* __restrict__ a, const float* __restrict__ scl,
    const float* __restrict__ W,
    float* __restrict__ zpart, float* __restrict__ ssOut,
    float* __restrict__ seedDst, const float* __restrict__ seedAdd,
    const float* __restrict__ seedBias,
    float* __restrict__ As, float* __restrict__ Ws) {
  const int cgi = vblk & 63, ks = vblk >> 6;   // 64 cg x 8 ks
  const int e0base = ks * 128;                 // e-slice of 128
  const int tx = tid & 31, ty = tid >> 5;
  const int ka = tid & 31, ba = tid >> 5;      // staging coords (k const/thread)
  const int m0 = cgi * 64;
  float acc[4][2] = {{0.f,0.f},{0.f,0.f},{0.f,0.f},{0.f,0.f}};
  float ssacc[4] = {0.f,0.f,0.f,0.f};
  const bool lead = (cgi == 0);
  const bool doSeed = lead && (seedDst != nullptr);
  const bool doAdd  = lead && (seedAdd != nullptr);

  float va[2][4], vw[2][8], vsa[2][4], vscl[2], vsb[2];
  // prefetch chunk 0
  {
    const int e0 = e0base;
#pragma unroll
    for (int j = 0; j < 4; ++j) va[0][j] = a[(ba + 8*j) * EE + e0 + ka];
    vscl[0] = scl[e0 + ka];
#pragma unroll
    for (int j = 0; j < 8; ++j)
      vw[0][j] = W[(size_t)(m0 + ba + 8*j) * EE + e0 + ka];
    if (doSeed) vsb[0] = seedBias[e0 + ka];
    if (doAdd) {
#pragma unroll
      for (int j = 0; j < 4; ++j) vsa[0][j] = seedAdd[(ba + 8*j) * EE + e0 + ka];
    }
  }
#pragma unroll
  for (int c = 0; c < 4; ++c) {
    const int cur = c & 1, nx = cur ^ 1;
    const int e0 = e0base + c * 32;
    if (c < 3) {  // issue next-chunk loads (latency hides under LDS+FMA below)
      const int e1 = e0 + 32;
#pragma unroll
      for (int j = 0; j < 4; ++j) va[nx][j] = a[(ba + 8*j) * EE + e1 + ka];
      vscl[nx] = scl[e1 + ka];
#pragma unroll
      for (int j = 0; j < 8; ++j)
        vw[nx][j] = W[(size_t)(m0 + ba + 8*j) * EE + e1 + ka];
      if (doSeed) vsb[nx] = seedBias[e1 + ka];
      if (doAdd) {
#pragma unroll
        for (int j = 0; j < 4; ++j) vsa[nx][j] = seedAdd[(ba + 8*j) * EE + e1 + ka];
      }
    }
    // stage current chunk to LDS (+ss/seed side effects)
#pragma unroll
    for (int j = 0; j < 4; ++j) {
      float v = va[cur][j];
      ssacc[j] += v * v;
      As[ka * 36 + ba + 8*j] = v * vscl[cur];
      if (doSeed) {
        float d = v + vsb[cur];
        if (doAdd) d += vsa[cur][j];
        seedDst[(ba + 8*j) * EE + e0 + ka] = d;
      }
    }
#pragma unroll
    for (int j = 0; j < 8; ++j) Ws[ka * 68 + ba + 8*j] = vw[cur][j];
    __syncthreads();
#pragma unroll
    for (int k = 0; k < 32; ++k) {
      float4 a4 = *(const float4*)&As[k * 36 + 4 * ty];
      float2 w2 = *(const float2*)&Ws[k * 68 + 2 * tx];
      acc[0][0] += a4.x * w2.x; acc[0][1] += a4.x * w2.y;
      acc[1][0] += a4.y * w2.x; acc[1][1] += a4.y * w2.y;
      acc[2][0] += a4.z * w2.x; acc[2][1] += a4.z * w2.y;
      acc[3][0] += a4.w * w2.x; acc[3][1] += a4.w * w2.y;
    }
    __syncthreads();
  }
  if (lead && ssOut) {
#pragma unroll
    for (int j = 0; j < 4; ++j) {
      float v = ssacc[j];
#pragma unroll
      for (int off = 16; off > 0; off >>= 1) v += __shfl_xor(v, off);
      if (tx == 0) atomicAdd(&ssOut[ty + 8 * j], v);
    }
  }
#pragma unroll
  for (int r = 0; r < 4; ++r) {
    size_t base = ((size_t)(4 * ty + r) * MM + m0 + 2 * tx) * 8 + ks;
    zpart[base]     = acc[r][0];
    zpart[base + 8] = acc[r][1];
  }
}

// fc2-style with prefetch: dest[b][n] += sum_{k in slice} y[b][k]*W2[n][k],
// y = silu(rinv_b * sum_{s<8} zp[b][k][s] + ybias[k]). 16cg x 32ks = 512 vblks.
__device__ inline void stage_fc2(int vblk, int tid,
    const float* __restrict__ zp, const float* __restrict__ ssIn,
    const float* __restrict__ ybias, const float* __restrict__ W2,
    float* __restrict__ dest, float* __restrict__ As, float* __restrict__ Ws) {
  const int cgi = vblk & 15, ks = vblk >> 4;   // 16 cg x 32 ks
  const int n0 = cgi * 64;
  const int tx = tid & 31, ty = tid >> 5;
  const int ka = tid & 31, ba = tid >> 5;
  float acc[4][2] = {{0.f,0.f},{0.f,0.f},{0.f,0.f},{0.f,0.f}};
  // rinv per staged row (ssIn ready after the stage-entry barrier; reused all chunks)
  float rinvj[4];
#pragma unroll
  for (int j = 0; j < 4; ++j)
    rinvj[j] = rsqrtf(ssIn[ba + 8*j] * (1.f / EE) + EPSF);

  float4 vz[2][4][2];
  float vw[2][8], vyb[2];
  {
    const int k0 = ks * 128;
#pragma unroll
    for (int j = 0; j < 4; ++j) {
      size_t zb = ((size_t)(ba + 8*j) * MM + k0 + ka) * 8;
      vz[0][j][0] = *(const float4*)&zp[zb];
      vz[0][j][1] = *(const float4*)&zp[zb + 4];
    }
    vyb[0] = ybias[k0 + ka];
#pragma unroll
    for (int j = 0; j < 8; ++j)
      vw[0][j] = W2[(size_t)(n0 + ba + 8*j) * MM + k0 + ka];
  }
#pragma unroll
  for (int c = 0; c < 4; ++c) {
    const int cur = c & 1, nx = cur ^ 1;
    if (c < 3) {
      const int k1 = ks * 128 + (c + 1) * 32;
#pragma unroll
      for (int j = 0; j < 4; ++j) {
        size_t zb = ((size_t)(ba + 8*j) * MM + k1 + ka) * 8;
        vz[nx][j][0] = *(const float4*)&zp[zb];
        vz[nx][j][1] = *(const float4*)&zp[zb + 4];
      }
      vyb[nx] = ybias[k1 + ka];
#pragma unroll
      for (int j = 0; j < 8; ++j)
        vw[nx][j] = W2[(size_t)(n0 + ba + 8*j) * MM + k1 + ka];
    }
#pragma unroll
    for (int j = 0; j < 4; ++j) {
      float4 z0 = vz[cur][j][0], z1 = vz[cur][j][1];
      float z = (z0.x + z0.y + z0.z + z0.w) + (z1.x + z1.y + z1.z + z1.w);
      float zz = z * rinvj[j] + vyb[cur];
      As[ka * 36 + ba + 8*j] = zz / (1.f + expf(-zz));
    }
#pragma unroll
    for (int j = 0; j < 8; ++j) Ws[ka * 68 + ba + 8*j] = vw[cur][j];
    __syncthreads();
#pragma unroll
    for (int k = 0; k < 32; ++k) {
      float4 a4 = *(const float4*)&As[k * 36 + 4 * ty];
      float2 w2 = *(const float2*)&Ws[k * 68 + 2 * tx];
      acc[0][0] += a4.x * w2.x; acc[0][1] += a4.x * w2.y;
      acc[1][0] += a4.y * w2.x; acc[1][1] += a4.y * w2.y;
      acc[2][0] += a4.z * w2.x; acc[2][1] += a4.z * w2.y;
      acc[3][0] += a4.w * w2.x; acc[3][1] += a4.w * w2.y;
    }
    __syncthreads();
  }
#pragma unroll
  for (int r = 0; r < 4; ++r) {
    atomicAdd(&dest[(4 * ty + r) * EE + n0 + 2 * tx], acc[r][0]);
    atomicAdd(&dest[(4 * ty + r) * EE + n0 + 2 * tx + 1], acc[r][1]);
  }
}

// nxt GEMM, full-K with prefetch: 64 active vblks x 16 cols. Each active vblk
// stages the full s row-block, computes its own ss (rinv), writes nxt and the
// carry inp_{t+1} = emb[tok] + nxt. vblk 0 persists raw ss for phase 2.
__device__ inline void stage_nxt(int vblk, int tid,
    const float* __restrict__ s, const float* __restrict__ nw,
    const float* __restrict__ Wn, const float* __restrict__ nb,
    float* __restrict__ nxt_out, float* __restrict__ ss_out,
    const int* __restrict__ tokens, const float* __restrict__ embw,
    float* __restrict__ inp_next, int tnext,
    float* __restrict__ Wt /*16x68 in As*/, float* __restrict__ Xs /*32x68 in Ws*/,
    float* __restrict__ ssrow /*32*/) {
  const bool act = (vblk < 64);
  const int col0 = vblk * 16;
  const int c = tid & 15;
  const int b = tid >> 4;            // 0..15 -> rows b, b+16
  const int ln = tid & 63, bw = tid >> 6;   // staging coords
  float acc0 = 0.f, acc1 = 0.f;
  float ssl[8] = {0.f,0.f,0.f,0.f,0.f,0.f,0.f,0.f};
  float vsl[2][8], vwn[2][4], vnw[2];
  if (act) {
#pragma unroll
    for (int j = 0; j < 8; ++j) vsl[0][j] = s[(bw + 4*j) * EE + ln];
    vnw[0] = nw[ln];
#pragma unroll
    for (int j = 0; j < 4; ++j)
      vwn[0][j] = Wn[(size_t)(col0 + bw + 4*j) * EE + ln];
  }
#pragma unroll
  for (int cc = 0; cc < 16; ++cc) {
    const int cur = cc & 1, nx = cur ^ 1;
    if (act && cc < 15) {
      const int k1 = (cc + 1) * 64;
#pragma unroll
      for (int j = 0; j < 8; ++j) vsl[nx][j] = s[(bw + 4*j) * EE + k1 + ln];
      vnw[nx] = nw[k1 + ln];
#pragma unroll
      for (int j = 0; j < 4; ++j)
        vwn[nx][j] = Wn[(size_t)(col0 + bw + 4*j) * EE + k1 + ln];
    }
    if (act) {
#pragma unroll
      for (int j = 0; j < 8; ++j) {
        float v = vsl[cur][j];
        ssl[j] += v * v;
        Xs[(bw + 4*j) * 68 + ln] = v * vnw[cur];
      }
#pragma unroll
      for (int j = 0; j < 4; ++j) Wt[(bw + 4*j) * 68 + ln] = vwn[cur][j];
    }
    __syncthreads();
    if (act) {
#pragma unroll
      for (int k = 0; k < 64; k += 4) {
        float4 w4 = *(const float4*)&Wt[c * 68 + k];
        float4 x0 = *(const float4*)&Xs[b * 68 + k];
        float4 x1 = *(const float4*)&Xs[(b + 16) * 68 + k];
        acc0 += x0.x * w4.x + x0.y * w4.y + x0.z * w4.z + x0.w * w4.w;
        acc1 += x1.x * w4.x + x1.y * w4.y + x1.z * w4.z + x1.w * w4.w;
      }
    }
    __syncthreads();
  }
  if (act) {
    const int wv = tid >> 6;
#pragma unroll
    for (int j = 0; j < 8; ++j) {
      float v = ssl[j];
#pragma unroll
      for (int off = 32; off > 0; off >>= 1) v += __shfl_xor(v, off);
      if ((tid & 63) == 0) ssrow[wv + 4 * j] = v;
    }
  }
  __syncthreads();
  if (act) {
    float rinv0 = rsqrtf(ssrow[b] * (1.f / EE) + EPSF);
    float rinv1 = rsqrtf(ssrow[b + 16] * (1.f / EE) + EPSF);
    float nv0 = acc0 * rinv0 + nb[col0 + c];
    float nv1 = acc1 * rinv1 + nb[col0 + c];
    nxt_out[b * EE + col0 + c] = nv0;
    nxt_out[(b + 16) * EE + col0 + c] = nv1;
    if (inp_next) {
      int tok0 = tokens[b * TT + tnext];
      int tok1 = tokens[(b + 16) * TT + tnext];
      inp_next[b * EE + col0 + c] = embw[(size_t)tok0 * EE + col0 + c] + nv0;
      inp_next[(b + 16) * EE + col0 + c] = embw[(size_t)tok1 * EE + col0 + c] + nv1;
    }
    if (vblk == 0 && tid < 32) ss_out[tid] = ssrow[tid];
  }
  __syncthreads();
}

__global__ __launch_bounds__(512, 2) void k_scan2(ScanParams p) {
  __shared__ __align__(16) float AsB[2][32 * 36];
  __shared__ __align__(16) float WsB[2][32 * 68];
  __shared__ float ssrowB[2][32];
  const int sub = threadIdx.x >> 8;
  const int tid = threadIdx.x & 255;
  const int vblk = blockIdx.x * 2 + sub;
  float* As = AsB[sub];
  float* Ws = WsB[sub];
  int sidx = 0;
  for (int t = 0; t < TT; ++t) {
    const float* inp = p.inp_all + (size_t)t * BE;
    float* s_t = p.s_all + (size_t)t * BE;
    // A: fc1 layer-0 partials (+seed hbuf = inp+fc2b0, ssA)
    stage_fc1(vblk, tid, inp, p.bnw, p.fc1w, p.zpart,
              p.ssA + t * BB, p.hbuf, nullptr, p.fc2b, As, Ws);
    gbar(p.cnt, sidx++, 256);
    // B: fc2 layer 0 -> hbuf (seeded atomics)
    stage_fc2(vblk, tid, p.zpart, p.ssA + t * BB, p.fc1b, p.fc2w, p.hbuf, As, Ws);
    gbar(p.cnt, sidx++, 256);
    // C: fc1 layer-1 partials (+seed s_t = hbuf+inp+fc2b1, ssH)
    stage_fc1(vblk, tid, p.hbuf, p.bnw + EE, p.fc1w + (size_t)MM * EE,
              p.zpart, p.ssH + t * BB, s_t, inp, p.fc2b + EE, As, Ws);
    gbar(p.cnt, sidx++, 256);
    // D: fc2 layer 1 -> s_t (seeded atomics)
    stage_fc2(vblk, tid, p.zpart, p.ssH + t * BB, p.fc1b + MM,
              p.fc2w + (size_t)EE * MM, s_t, As, Ws);
    gbar(p.cnt, sidx++, 256);
    // E: nxt GEMM full-K + finalize carry (merged)
    stage_nxt(vblk, tid, s_t, p.nw, p.nxtw, p.nxtb,
              p.nxt_all + (size_t)t * BE, p.ssS + t * BB,
              p.tokens, p.embw,
              (t + 1 < TT) ? p.inp_all + (size_t)(t + 1) * BE : nullptr,
              t + 1, As, Ws, ssrowB[sub]);
    gbar(p.cnt, sidx++, 256);
  }
}

// ======================= small helpers =======================

__global__ void k_zero(float* __restrict__ p, int n) {
  int i = blockIdx.x * 256 + threadIdx.x;
  if (i < n) p[i] = 0.f;
}

__global__ void k_init(const int* __restrict__ tokens,
                       const float* __restrict__ embw,
                       float* __restrict__ inp0) {
  int b = blockIdx.x;
  int tok = tokens[b * TT];
  for (int e = threadIdx.x; e < EE; e += 256)
    inp0[b * EE + e] = embw[(size_t)tok * EE + e];
}

// ======================= legacy fallback (round-1, proven) =======================

__global__ __launch_bounds__(256)
void k_fc1(const float* __restrict__ h, const float* __restrict__ bnw,
           const float* __restrict__ W, const float* __restrict__ bias,
           float* __restrict__ yout, float* __restrict__ initDst,
           const float* __restrict__ initAdd, const float* __restrict__ initBias) {
  __shared__ __align__(16) float Hs[32][68];
  __shared__ __align__(16) float Ws[8][68];
  __shared__ float ssrow[32];
  const int tid = threadIdx.x;
  const int col0 = blockIdx.x * 8;
  const int c = tid & 7;
  const int b = tid >> 3;
  const bool writer = (blockIdx.x == 0);
  float acc = 0.f;
  float ssl[8];
#pragma unroll
  for (int j = 0; j < 8; ++j) ssl[j] = 0.f;
  for (int kc = 0; kc < EE; kc += 64) {
#pragma unroll
    for (int j = 0; j < 8; ++j) {
      int i = tid + j * 256;
      int bb = i >> 6, k = i & 63;
      float v = h[bb * EE + kc + k];
      ssl[j] += v * v;
      Hs[bb][k] = v * bnw[kc + k];
      if (writer) {
        float d = v + initBias[kc + k];
        if (initAdd) d += initAdd[bb * EE + kc + k];
        initDst[bb * EE + kc + k] = d;
      }
    }
#pragma unroll
    for (int j = 0; j < 2; ++j) {
      int i = tid + j * 256;
      int cc = i >> 6, k = i & 63;
      Ws[cc][k] = W[(size_t)(col0 + cc) * EE + kc + k];
    }
    __syncthreads();
#pragma unroll
    for (int k = 0; k < 64; k += 4) {
      float4 w4 = *(const float4*)&Ws[c][k];
      float4 h4 = *(const float4*)&Hs[b][k];
      acc += h4.x * w4.x + h4.y * w4.y + h4.z * w4.z + h4.w * w4.w;
    }
    __syncthreads();
  }
  const int wv = tid >> 6;
#pragma unroll
  for (int j = 0; j < 8; ++j) {
    float v = ssl[j];
#pragma unroll
    for (int off = 32; off > 0; off >>= 1) v += __shfl_xor(v, off);
    if ((tid & 63) == 0) ssrow[wv + 4 * j] = v;
  }
  __syncthreads();
  float rinv = rsqrtf(ssrow[b] * (1.f / EE) + EPSF);
  float z = acc * rinv + bias[col0 + c];
  yout[b * MM + col0 + c] = z / (1.f + expf(-z));
}

__global__ __launch_bounds__(256)
void k_fc2(const float* __restrict__ y, const float* __restrict__ W2,
           float* __restrict__ dest) {
  __shared__ __align__(16) float Ys[32][68];
  __shared__ __align__(16) float Ws[16][68];
  const int tid = threadIdx.x;
  const int cgi = blockIdx.x & 63;
  const int ks = blockIdx.x >> 6;
  const int col0 = cgi * 16;
  const int c = tid & 15;
  const int bq = tid >> 4;
  float acc0 = 0.f, acc1 = 0.f;
  const int kend = ks * 512 + 512;
  for (int kc = ks * 512; kc < kend; kc += 64) {
#pragma unroll
    for (int j = 0; j < 8; ++j) {
      int i = tid + j * 256;
      int bb = i >> 6, k = i & 63;
      Ys[bb][k] = y[bb * MM + kc + k];
    }
#pragma unroll
    for (int j = 0; j < 4; ++j) {
      int i = tid + j * 256;
      int cc = i >> 6, k = i & 63;
      Ws[cc][k] = W2[(size_t)(col0 + cc) * MM + kc + k];
    }
    __syncthreads();
#pragma unroll
    for (int k = 0; k < 64; k += 4) {
      float4 w4 = *(const float4*)&Ws[c][k];
      float4 a4 = *(const float4*)&Ys[bq][k];
      float4 b4 = *(const float4*)&Ys[bq + 16][k];
      acc0 += a4.x * w4.x + a4.y * w4.y + a4.z * w4.z + a4.w * w4.w;
      acc1 += b4.x * w4.x + b4.y * w4.y + b4.z * w4.z + b4.w * w4.w;
    }
    __syncthreads();
  }
  atomicAdd(&dest[bq * EE + col0 + c], acc0);
  atomicAdd(&dest[(bq + 16) * EE + col0 + c], acc1);
}

__global__ __launch_bounds__(256)
void k_nxt(const float* __restrict__ s, const float* __restrict__ nw,
           const float* __restrict__ Wn, const float* __restrict__ nb,
           float* __restrict__ nxt_out, float* __restrict__ ss_out,
           const int* __restrict__ tokens, const float* __restrict__ embw,
           float* __restrict__ inp_next, int tnext) {
  __shared__ __align__(16) float Xs[32][68];
  __shared__ __align__(16) float Ws[8][68];
  __shared__ float ssrow[32];
  const int tid = threadIdx.x;
  const int col0 = blockIdx.x * 8;
  const int c = tid & 7;
  const int b = tid >> 3;
  float acc = 0.f;
  float ssl[8];
#pragma unroll
  for (int j = 0; j < 8; ++j) ssl[j] = 0.f;
  for (int kc = 0; kc < EE; kc += 64) {
#pragma unroll
    for (int j = 0; j < 8; ++j) {
      int i = tid + j * 256;
      int bb = i >> 6, k = i & 63;
      float v = s[bb * EE + kc + k];
      ssl[j] += v * v;
      Xs[bb][k] = v * nw[kc + k];
    }
#pragma unroll
    for (int j = 0; j < 2; ++j) {
      int i = tid + j * 256;
      int cc = i >> 6, k = i & 63;
      Ws[cc][k] = Wn[(size_t)(col0 + cc) * EE + kc + k];
    }
    __syncthreads();
#pragma unroll
    for (int k = 0; k < 64; k += 4) {
      float4 w4 = *(const float4*)&Ws[c][k];
      float4 h4 = *(const float4*)&Xs[b][k];
      acc += h4.x * w4.x + h4.y * w4.y + h4.z * w4.z + h4.w * w4.w;
    }
    __syncthreads();
  }
  const int wv = tid >> 6;
#pragma unroll
  for (int j = 0; j < 8; ++j) {
    float v = ssl[j];
#pragma unroll
    for (int off = 32; off > 0; off >>= 1) v += __shfl_xor(v, off);
    if ((tid & 63) == 0) {
      ssrow[wv + 4 * j] = v;
      if (blockIdx.x == 0) ss_out[wv + 4 * j] = v;
    }
  }
  __syncthreads();
  float rinv = rsqrtf(ssrow[b] * (1.f / EE) + EPSF);
  float nv = acc * rinv + nb[col0 + c];
  nxt_out[b * EE + col0 + c] = nv;
  if (inp_next) {
    int tok = tokens[b * TT + tnext];
    inp_next[b * EE + col0 + c] = embw[(size_t)tok * EE + col0 + c] + nv;
  }
}

// ======================= phase 2 =======================

__global__ __launch_bounds__(256)
void k_curemb(const float* __restrict__ s_all, const float* __restrict__ ss_s,
              const float* __restrict__ nw, const float* __restrict__ Wc,
              const float* __restrict__ cb, const float* __restrict__ inp_all,
              float* __restrict__ cur_out, float* __restrict__ aux_accum) {
  __shared__ __align__(16) float As[16][68];
  __shared__ __align__(16) float Bs[16][68];
  __shared__ float rr[64];
  __shared__ float wred[4];
  const int tid = threadIdx.x;
  const int rt = blockIdx.x & 127;
  const int ct = blockIdx.x >> 7;
  const int row0 = rt * 64, col0 = ct * 64;
  if (tid < 64) rr[tid] = rsqrtf(ss_s[row0 + tid] * (1.f / EE) + EPSF);
  __syncthreads();
  float acc[4][4];
#pragma unroll
  for (int i = 0; i < 4; ++i)
#pragma unroll
    for (int j = 0; j < 4; ++j) acc[i][j] = 0.f;
  const int tx = tid & 15, ty = tid >> 4;
  for (int kc = 0; kc < EE; kc += 16) {
#pragma unroll
    for (int j = 0; j < 4; ++j) {
      int i = tid + j * 256;
      int k = i & 15, m = i >> 4;
      As[k][m] = s_all[(size_t)(row0 + m) * EE + kc + k] * rr[m] * nw[kc + k];
      Bs[k][m] = Wc[(size_t)(col0 + m) * EE + kc + k];
    }
    __syncthreads();
#pragma unroll
    for (int k = 0; k < 16; ++k) {
      float4 a4 = *(const float4*)&As[k][tx * 4];
      float4 b4 = *(const float4*)&Bs[k][ty * 4];
      acc[0][0] += a4.x*b4.x; acc[0][1] += a4.x*b4.y; acc[0][2] += a4.x*b4.z; acc[0][3] += a4.x*b4.w;
      acc[1][0] += a4.y*b4.x; acc[1][1] += a4.y*b4.y; acc[1][2] += a4.y*b4.z; acc[1][3] += a4.y*b4.w;
      acc[2][0] += a4.z*b4.x; acc[2][1] += a4.z*b4.y; acc[2][2] += a4.z*b4.z; acc[2][3] += a4.z*b4.w;
      acc[3][0] += a4.w*b4.x; acc[3][1] += a4.w*b4.y; acc[3][2] += a4.w*b4.z; acc[3][3] += a4.w*b4.w;
    }
    __syncthreads();
  }
  float auxp = 0.f;
#pragma unroll
  for (int i = 0; i < 4; ++i) {
    int r = row0 + tx * 4 + i;
#pragma unroll
    for (int j = 0; j < 4; ++j) {
      int col = col0 + ty * 4 + j;
      float v = acc[i][j] + cb[col];
      cur_out[(size_t)r * EE + col] = v;
      float d = v - inp_all[(size_t)r * EE + col];
      auxp += d * d;
    }
  }
#pragma unroll
  for (int off = 32; off > 0; off >>= 1) auxp += __shfl_xor(auxp, off);
  if ((tid & 63) == 0) wred[tid >> 6] = auxp;
  __syncthreads();
  if (tid == 0) atomicAdd(aux_accum, wred[0] + wred[1] + wred[2] + wred[3]);
}

__global__ __launch_bounds__(256)
void k_logits(const float* __restrict__ A, const float* __restrict__ embw,
              const int* __restrict__ idxs, float* __restrict__ rowsum,
              float* __restrict__ lidx, float* __restrict__ store) {
  __shared__ __align__(16) float As[16][68];
  __shared__ __align__(16) float Bs[16][68];
  __shared__ float rowpart[64];
  const int tid = threadIdx.x;
  const int rt = blockIdx.x & 127;
  const int ct = blockIdx.x >> 7;
  const int row0 = rt * 64, col0 = ct * 64;
  float acc[4][4];
#pragma unroll
  for (int i = 0; i < 4; ++i)
#pragma unroll
    for (int j = 0; j < 4; ++j) acc[i][j] = 0.f;
  const int tx = tid & 15, ty = tid >> 4;
  for (int kc = 0; kc < EE; kc += 16) {
#pragma unroll
    for (int j = 0; j < 4; ++j) {
      int i = tid + j * 256;
      int k = i & 15, m = i >> 4;
      As[k][m] = A[(size_t)(row0 + m) * EE + kc + k];
      Bs[k][m] = embw[(size_t)(col0 + m) * EE + kc + k];
    }
    __syncthreads();
#pragma unroll
    for (int k = 0; k < 16; ++k) {
      float4 a4 = *(const float4*)&As[k][tx * 4];
      float4 b4 = *(const float4*)&Bs[k][ty * 4];
      acc[0][0] += a4.x*b4.x; acc[0][1] += a4.x*b4.y; acc[0][2] += a4.x*b4.z; acc[0][3] += a4.x*b4.w;
      acc[1][0] += a4.y*b4.x; acc[1][1] += a4.y*b4.y; acc[1][2] += a4.y*b4.z; acc[1][3] += a4.y*b4.w;
      acc[2][0] += a4.z*b4.x; acc[2][1] += a4.z*b4.y; acc[2][2] += a4.z*b4.z; acc[2][3] += a4.z*b4.w;
      acc[3][0] += a4.w*b4.x; acc[3][1] += a4.w*b4.y; acc[3][2] += a4.w*b4.z; acc[3][3] += a4.w*b4.w;
    }
    __syncthreads();
  }
  if (tid < 64) rowpart[tid] = 0.f;
  __syncthreads();
#pragma unroll
  for (int i = 0; i < 4; ++i) {
    int r = row0 + tx * 4 + i;
    int t = r >> 5, bb = r & 31;
    int idx = idxs[bb * TT + t];
    float e0 = expf(acc[i][0]);
    float e1 = expf(acc[i][1]);
    float e2 = expf(acc[i][2]);
    float e3 = expf(acc[i][3]);
    atomicAdd(&rowpart[tx * 4 + i], e0 + e1 + e2 + e3);
    int cbase = col0 + ty * 4;
#pragma unroll
    for (int j = 0; j < 4; ++j)
      if (cbase + j == idx) lidx[r] = acc[i][j];
    if (store) {
      float4 o = make_float4(acc[i][0], acc[i][1], acc[i][2], acc[i][3]);
      *(float4*)(store + ((size_t)bb * TT + t) * VV + cbase) = o;
    }
  }
  __syncthreads();
  if (tid < 64) atomicAdd(&rowsum[row0 + tid], rowpart[tid]);
}

__global__ void k_final(const float* __restrict__ rs_cur,
                        const float* __restrict__ rs_nxt,
                        const float* __restrict__ ltok,
                        const float* __restrict__ ltgt,
                        const float* __restrict__ aux_accum,
                        float* __restrict__ out) {
  float p = 0.f;
  for (int r = threadIdx.x; r < NROWS; r += 256)
    p += (ltok[r] - logf(rs_cur[r])) + (ltgt[r] - logf(rs_nxt[r]));
#pragma unroll
  for (int off = 32; off > 0; off >>= 1) p += __shfl_xor(p, off);
  __shared__ float w[4];
  if ((threadIdx.x & 63) == 0) w[threadIdx.x >> 6] = p;
  __syncthreads();
  if (threadIdx.x == 0) {
    float tot = w[0] + w[1] + w[2] + w[3];
    out[0] = -tot / (2.f * (float)NROWS);
    out[1] = aux_accum[0] * (1.f / ((float)NROWS * EE));
  }
}

// ======================= launch =======================

extern "C" void kernel_launch(void* const* d_in, const int* in_sizes, int n_in,
                              void* d_out, int out_size, void* d_ws, size_t ws_size,
                              hipStream_t stream) {
  (void)in_sizes; (void)n_in; (void)out_size; (void)ws_size;
  const int*   tokens  = (const int*)d_in[0];
  const int*   targets = (const int*)d_in[1];
  const float* embw    = (const float*)d_in[2];
  const float* bnw     = (const float*)d_in[3];
  const float* fc1w    = (const float*)d_in[4];
  const float* fc1b    = (const float*)d_in[5];
  const float* fc2w    = (const float*)d_in[6];
  const float* fc2b    = (const float*)d_in[7];
  const float* nw      = (const float*)d_in[8];
  const float* curw    = (const float*)d_in[9];
  const float* curb    = (const float*)d_in[10];
  const float* nxtw    = (const float*)d_in[11];
  const float* nxtb    = (const float*)d_in[12];
  float* out = (float*)d_out;

  // d_out doubles as scratch for three [8192][1024] fp32 activations; the
  // final logits GEMM overwrites all of it with the real output.
  float* cur_all = out;
  float* s_all   = out + (size_t)NROWS * EE;
  float* inp_all = out + 2 * (size_t)NROWS * EE;

  float* ws      = (float*)d_ws;
  float* nxt_all = ws;                                   // 8,388,608
  float* zpart   = nxt_all + (size_t)NROWS * EE;         // 1,048,576
  float* hbuf    = zpart + 1048576;                      // 32,768
  float* cntf    = hbuf + BE;                            // 2,048 (barrier cnt)
  float* ssA     = cntf + 2048;                          // 8,192
  float* ssH     = ssA + TT * BB;                        // 8,192
  float* ssS     = ssH + TT * BB;                        // 8,192
  float* rs_cur  = ssS + TT * BB;                        // 8,192
  float* rs_nxt  = rs_cur + NROWS;                       // 8,192
  float* auxac   = rs_nxt + NROWS;                       // 1
  float* ltok    = auxac + 1;                            // 8,192
  float* ltgt    = ltok + NROWS;                         // 8,192
  float* ybuf    = ltgt + NROWS;                         // 131,072 (fallback)

  // zero: barrier counters + ssA/ssH/ssS + rs_cur/rs_nxt + auxac (contiguous)
  const int nzero = 2048 + 3 * TT * BB + 2 * NROWS + 1;
  k_zero<<<(nzero + 255) / 256, 256, 0, stream>>>(cntf, nzero);
  k_init<<<32, 256, 0, stream>>>(tokens, embw, inp_all);

  ScanParams p;
  p.tokens = tokens; p.embw = embw; p.bnw = bnw;
  p.fc1w = fc1w; p.fc1b = fc1b; p.fc2w = fc2w; p.fc2b = fc2b;
  p.nw = nw; p.nxtw = nxtw; p.nxtb = nxtb;
  p.inp_all = inp_all; p.s_all = s_all; p.nxt_all = nxt_all;
  p.zpart = zpart; p.hbuf = hbuf;
  p.ssA = ssA; p.ssH = ssH; p.ssS = ssS;
  p.cnt = (unsigned*)cntf;

  void* args[] = { &p };
  hipError_t err = hipLaunchCooperativeKernel((const void*)k_scan2,
                                              dim3(256), dim3(512),
                                              args, 0, stream);
  if (err != hipSuccess) {
    // Fallback: proven round-1 multi-kernel sequence.
    for (int t = 0; t < TT; ++t) {
      const float* inp = inp_all + (size_t)t * BE;
      float* s = s_all + (size_t)t * BE;
      k_fc1<<<512, 256, 0, stream>>>(inp, bnw, fc1w, fc1b, ybuf,
                                     hbuf, nullptr, fc2b);
      k_fc2<<<512, 256, 0, stream>>>(ybuf, fc2w, hbuf);
      k_fc1<<<512, 256, 0, stream>>>(hbuf, bnw + EE, fc1w + (size_t)MM * EE,
                                     fc1b + MM, ybuf, s, inp, fc2b + EE);
      k_fc2<<<512, 256, 0, stream>>>(ybuf, fc2w + (size_t)EE * MM, s);
      k_nxt<<<128, 256, 0, stream>>>(s, nw, nxtw, nxtb,
                                     nxt_all + (size_t)t * BE, ssS + t * BB,
                                     tokens, embw,
                                     (t + 1 < TT) ? inp_all + (size_t)(t + 1) * BE : nullptr,
                                     t + 1);
    }
  }

  k_curemb<<<2048, 256, 0, stream>>>(s_all, ssS, nw, curw, curb, inp_all,
                                     cur_all, auxac);
  k_logits<<<8192, 256, 0, stream>>>(cur_all, embw, tokens, rs_cur, ltok, nullptr);
  k_logits<<<8192, 256, 0, stream>>>(nxt_all, embw, targets, rs_nxt, ltgt, out);
  k_final<<<1, 256, 0, stream>>>(rs_cur, rs_nxt, ltok, ltgt, auxac,
                                 out + (size_t)NROWS * VV);
}

// Round 6
// 31628.308 us; speedup vs baseline: 10.6755x; 10.6755x over previous
//
#include <hip/hip_runtime.h>
#include <math.h>

#define TT  256
#define BB  32
#define EE  1024
#define MM  4096
#define VV  4096
#define BE  (BB*EE)
#define NROWS (TT*BB)
#define EPSF 1.1920929e-07f

typedef _Float16 h2 __attribute__((ext_vector_type(2)));

__device__ inline float dot2f(h2 a, h2 b, float c) {
#if __has_builtin(__builtin_amdgcn_fdot2)
  return __builtin_amdgcn_fdot2(a, b, c, false);
#else
  return c + (float)a[0] * (float)b[0] + (float)a[1] * (float)b[1];
#endif
}

// ============ hierarchical grid barrier (fresh counters per barrier) ============
__device__ inline void gbar3(unsigned* gcnt, unsigned* mcnt, int sidx) {
  __syncthreads();
  if (threadIdx.x == 0) {
    const int g = blockIdx.x & 7;
    unsigned* gp = &gcnt[(sidx * 8 + g) * 32];
    unsigned* mp = &mcnt[sidx * 32];
    __builtin_amdgcn_fence(__ATOMIC_RELEASE, "agent");
    unsigned old = __hip_atomic_fetch_add(gp, 1u, __ATOMIC_RELAXED,
                                          __HIP_MEMORY_SCOPE_AGENT);
    if (old == 31u)
      __hip_atomic_fetch_add(mp, 1u, __ATOMIC_RELAXED, __HIP_MEMORY_SCOPE_AGENT);
    while (__hip_atomic_load(mp, __ATOMIC_RELAXED, __HIP_MEMORY_SCOPE_AGENT) < 8u)
      __builtin_amdgcn_s_sleep(1);
    __builtin_amdgcn_fence(__ATOMIC_ACQUIRE, "agent");
  }
  __syncthreads();
}

// ============ LDS-resident-weight GEMM core ============
// 512 threads; NR output rows/block (full-K dots); K = NCH*128.
// Input staged per 128-e chunk into double-buffered xs[64][33] h2 (bank-padded).
// Weights wl: LDS h2 [NR][K/2]. Returns z for thread (b2,m2) (tid < 32*NR).
template<int NR, int NCH, bool SCALED>
__device__ float gemm_core(int tid,
    const float* __restrict__ srcf, const h2* __restrict__ srch, int ldk,
    const float* __restrict__ scl, const float* __restrict__ rinv32,
    const h2* __restrict__ wl, h2* __restrict__ xs, float* __restrict__ red) {
  const int b = tid & 31, kq = tid >> 5;
  const int sb = tid >> 4, se = (tid & 15) * 8;
  const int WROW = NCH * 64;
  float acc[NR];
#pragma unroll
  for (int m = 0; m < NR; ++m) acc[m] = 0.f;

  auto stage = [&](int c) {
    h2* dst = xs + (c & 1) * (64 * 33);
    h2 p0, p1, p2, p3;
    if (SCALED) {
      const float4 v0 = *(const float4*)&srcf[sb * ldk + c * 128 + se];
      const float4 v1 = *(const float4*)&srcf[sb * ldk + c * 128 + se + 4];
      const float4 s0 = *(const float4*)&scl[c * 128 + se];
      const float4 s1 = *(const float4*)&scl[c * 128 + se + 4];
      const float ri = rinv32[sb];
      p0[0] = (_Float16)(v0.x * s0.x * ri); p0[1] = (_Float16)(v0.y * s0.y * ri);
      p1[0] = (_Float16)(v0.z * s0.z * ri); p1[1] = (_Float16)(v0.w * s0.w * ri);
      p2[0] = (_Float16)(v1.x * s1.x * ri); p2[1] = (_Float16)(v1.y * s1.y * ri);
      p3[0] = (_Float16)(v1.z * s1.z * ri); p3[1] = (_Float16)(v1.w * s1.w * ri);
    } else {
      const h2* sp = &srch[sb * (ldk / 2) + c * 64 + (tid & 15) * 4];
      p0 = sp[0]; p1 = sp[1]; p2 = sp[2]; p3 = sp[3];
    }
    const int ep0 = (tid & 15) * 4;
    dst[(ep0 + 0) * 33 + sb] = p0;
    dst[(ep0 + 1) * 33 + sb] = p1;
    dst[(ep0 + 2) * 33 + sb] = p2;
    dst[(ep0 + 3) * 33 + sb] = p3;
  };

  stage(0);
  __syncthreads();
  for (int c = 0; c < NCH; ++c) {
    if (c + 1 < NCH) stage(c + 1);
    const h2* xb = xs + (c & 1) * (64 * 33);
    const h2 x0 = xb[(kq * 4 + 0) * 33 + b];
    const h2 x1 = xb[(kq * 4 + 1) * 33 + b];
    const h2 x2 = xb[(kq * 4 + 2) * 33 + b];
    const h2 x3 = xb[(kq * 4 + 3) * 33 + b];
#pragma unroll
    for (int m = 0; m < NR; ++m) {
      const h2* wp = &wl[m * WROW + c * 64 + kq * 4];
      float a = acc[m];
      a = dot2f(x0, wp[0], a);
      a = dot2f(x1, wp[1], a);
      a = dot2f(x2, wp[2], a);
      a = dot2f(x3, wp[3], a);
      acc[m] = a;
    }
    __syncthreads();
  }
  // reduce over 16 kq groups: pairwise shuffle (kq bit0 = lane bit5), then LDS
#pragma unroll
  for (int m = 0; m < NR; ++m) acc[m] += __shfl_xor(acc[m], 32);
  const int wv = tid >> 6, ln = tid & 63;
  if (ln < 32) {
#pragma unroll
    for (int m = 0; m < NR; ++m) red[wv * 544 + ln * 17 + m] = acc[m];
  }
  __syncthreads();
  float z = 0.f;
  if (tid < 32 * NR) {
    const int b2 = (NR == 16) ? (tid >> 4) : (tid >> 2);
    const int m2 = tid & (NR - 1);
#pragma unroll
    for (int w = 0; w < 8; ++w) z += red[w * 544 + b2 * 17 + m2];
  }
  return z;
}

struct Scan3Params {
  const int* tokens;
  const float* embw;
  const float* bnw;
  const float* fc1w;
  const float* fc1b;
  const float* fc2w;
  const float* fc2b;
  const float* nw;
  const float* nxtw;
  const float* nxtb;
  float* inp_all;   // [TT][32][EE] (d_out)
  float* s_all;     // [TT][32][EE] (d_out)
  float* nxt_all;   // [TT][32][EE] (ws)
  _Float16* yh;     // [32][MM] fp16 activations (ws)
  float* hbuf;      // [32][EE]
  float* ssA;       // [TT+1][32]
  float* ssH;       // [TT][32]
  float* ssS;       // [TT][32]
  unsigned* gcnt;
  unsigned* mcnt;
};

__global__ __launch_bounds__(512, 1) void k_scan3(Scan3Params p) {
  extern __shared__ __align__(16) char smem[];
  h2* w1a = (h2*)smem;                      // [16][512]
  h2* w1b = (h2*)(smem + 32768);            // [16][512]
  h2* w2a = (h2*)(smem + 65536);            // [4][2048]
  h2* w2b = (h2*)(smem + 98304);            // [4][2048]
  h2* wn  = (h2*)(smem + 131072);           // [4][512]
  h2* xs  = (h2*)(smem + 139264);           // union: 2x[64][33] h2
  float* red = (float*)(smem + 139264);     // union: [8][32][17] f32
  float* rinv32 = (float*)(smem + 156672);  // [32]
  const int tid = threadIdx.x;
  const int cu = blockIdx.x;

  // ---- one-time: convert this CU's weight slices fp32 -> fp16 LDS ----
#pragma unroll 4
  for (int r = 0; r < 16; ++r) {
    float2 f = *(const float2*)&p.fc1w[((size_t)(cu * 16 + r)) * EE + tid * 2];
    h2 h; h[0] = (_Float16)f.x; h[1] = (_Float16)f.y;
    w1a[r * 512 + tid] = h;
    float2 g = *(const float2*)&p.fc1w[(size_t)MM * EE +
                                       ((size_t)(cu * 16 + r)) * EE + tid * 2];
    h2 h2v; h2v[0] = (_Float16)g.x; h2v[1] = (_Float16)g.y;
    w1b[r * 512 + tid] = h2v;
  }
#pragma unroll
  for (int r = 0; r < 4; ++r)
#pragma unroll
    for (int j = 0; j < 4; ++j) {
      int idx = tid + j * 512;
      float2 f = *(const float2*)&p.fc2w[((size_t)(cu * 4 + r)) * MM + idx * 2];
      h2 h; h[0] = (_Float16)f.x; h[1] = (_Float16)f.y;
      w2a[r * 2048 + idx] = h;
      float2 g = *(const float2*)&p.fc2w[(size_t)EE * MM +
                                         ((size_t)(cu * 4 + r)) * MM + idx * 2];
      h2 h2v; h2v[0] = (_Float16)g.x; h2v[1] = (_Float16)g.y;
      w2b[r * 2048 + idx] = h2v;
    }
#pragma unroll
  for (int r = 0; r < 4; ++r) {
    float2 f = *(const float2*)&p.nxtw[((size_t)(cu * 4 + r)) * EE + tid * 2];
    h2 h; h[0] = (_Float16)f.x; h[1] = (_Float16)f.y;
    wn[r * 512 + tid] = h;
  }
  __syncthreads();

  int sidx = 0;
  for (int t = 0; t < TT; ++t) {
    const float* inp = p.inp_all + (size_t)t * BE;
    float* s_t = p.s_all + (size_t)t * BE;

    // ---- A: fc1 L0: y = silu(rms(inp,bnw0) @ w1a^T + b1) ----
    if (tid < 32) rinv32[tid] = rsqrtf(p.ssA[t * 32 + tid] * (1.f / EE) + EPSF);
    __syncthreads();
    {
      float z = gemm_core<16, 8, true>(tid, inp, nullptr, EE, p.bnw, rinv32,
                                       w1a, xs, red);
      const int b2 = tid >> 4, m2 = tid & 15, gm = cu * 16 + m2;
      float zz = z + p.fc1b[gm];
      p.yh[b2 * MM + gm] = (_Float16)(zz / (1.f + expf(-zz)));
    }
    gbar3(p.gcnt, p.mcnt, sidx++);

    // ---- B: h = inp + y @ w2a^T + b2 ; ssH ----
    {
      float z = gemm_core<4, 32, false>(tid, nullptr, (const h2*)p.yh, MM,
                                        nullptr, nullptr, w2a, xs, red);
      if (tid < 128) {
        const int b2 = tid >> 2, m2 = tid & 3, gn = cu * 4 + m2;
        float hv = inp[b2 * EE + gn] + z + p.fc2b[gn];
        p.hbuf[b2 * EE + gn] = hv;
        float ssp = hv * hv;
        ssp += __shfl_xor(ssp, 1);
        ssp += __shfl_xor(ssp, 2);
        if (m2 == 0) atomicAdd(&p.ssH[t * 32 + b2], ssp);
      }
    }
    gbar3(p.gcnt, p.mcnt, sidx++);

    // ---- C: fc1 L1 on h ----
    if (tid < 32) rinv32[tid] = rsqrtf(p.ssH[t * 32 + tid] * (1.f / EE) + EPSF);
    __syncthreads();
    {
      float z = gemm_core<16, 8, true>(tid, p.hbuf, nullptr, EE, p.bnw + EE,
                                       rinv32, w1b, xs, red);
      const int b2 = tid >> 4, m2 = tid & 15, gm = cu * 16 + m2;
      float zz = z + p.fc1b[MM + gm];
      p.yh[b2 * MM + gm] = (_Float16)(zz / (1.f + expf(-zz)));
    }
    gbar3(p.gcnt, p.mcnt, sidx++);

    // ---- D: s = h + y @ w2b^T + b2' ; ssS ----
    {
      float z = gemm_core<4, 32, false>(tid, nullptr, (const h2*)p.yh, MM,
                                        nullptr, nullptr, w2b, xs, red);
      if (tid < 128) {
        const int b2 = tid >> 2, m2 = tid & 3, gn = cu * 4 + m2;
        float sv = p.hbuf[b2 * EE + gn] + z + p.fc2b[EE + gn];
        s_t[b2 * EE + gn] = sv;
        float ssp = sv * sv;
        ssp += __shfl_xor(ssp, 1);
        ssp += __shfl_xor(ssp, 2);
        if (m2 == 0) atomicAdd(&p.ssS[t * 32 + b2], ssp);
      }
    }
    gbar3(p.gcnt, p.mcnt, sidx++);

    // ---- E: nxt = rms(s,nw) @ wn^T + nb ; carry inp_{t+1}; ssA[t+1] ----
    if (tid < 32) rinv32[tid] = rsqrtf(p.ssS[t * 32 + tid] * (1.f / EE) + EPSF);
    __syncthreads();
    {
      float z = gemm_core<4, 8, true>(tid, s_t, nullptr, EE, p.nw, rinv32,
                                      wn, xs, red);
      if (tid < 128) {
        const int b2 = tid >> 2, m2 = tid & 3, gn = cu * 4 + m2;
        float nv = z + p.nxtb[gn];
        p.nxt_all[(size_t)t * BE + b2 * EE + gn] = nv;
        if (t + 1 < TT) {
          int tok = p.tokens[b2 * TT + t + 1];
          float iv = p.embw[(size_t)tok * EE + gn] + nv;
          p.inp_all[(size_t)(t + 1) * BE + b2 * EE + gn] = iv;
          float ssp = iv * iv;
          ssp += __shfl_xor(ssp, 1);
          ssp += __shfl_xor(ssp, 2);
          if (m2 == 0) atomicAdd(&p.ssA[(t + 1) * 32 + b2], ssp);
        }
      }
    }
    gbar3(p.gcnt, p.mcnt, sidx++);
  }
}

// ======================= helpers =======================

__global__ void k_zero(float* __restrict__ p, int n) {
  int i = blockIdx.x * 256 + threadIdx.x;
  if (i < n) p[i] = 0.f;
}

__global__ void k_init2(const int* __restrict__ tokens,
                        const float* __restrict__ embw,
                        float* __restrict__ inp0, float* __restrict__ ssA0) {
  int b = blockIdx.x;
  int tok = tokens[b * TT];
  int e = threadIdx.x * 4;
  float4 v = *(const float4*)&embw[(size_t)tok * EE + e];
  *(float4*)&inp0[b * EE + e] = v;
  float ss = v.x * v.x + v.y * v.y + v.z * v.z + v.w * v.w;
#pragma unroll
  for (int off = 32; off > 0; off >>= 1) ss += __shfl_xor(ss, off);
  __shared__ float w[4];
  if ((threadIdx.x & 63) == 0) w[threadIdx.x >> 6] = ss;
  __syncthreads();
  if (threadIdx.x == 0) ssA0[b] = w[0] + w[1] + w[2] + w[3];
}

// ======================= legacy fallback (round-1, proven) =======================

__global__ __launch_bounds__(256)
void k_fc1(const float* __restrict__ h, const float* __restrict__ bnw,
           const float* __restrict__ W, const float* __restrict__ bias,
           float* __restrict__ yout, float* __restrict__ initDst,
           const float* __restrict__ initAdd, const float* __restrict__ initBias) {
  __shared__ __align__(16) float Hs[32][68];
  __shared__ __align__(16) float Ws[8][68];
  __shared__ float ssrow[32];
  const int tid = threadIdx.x;
  const int col0 = blockIdx.x * 8;
  const int c = tid & 7;
  const int b = tid >> 3;
  const bool writer = (blockIdx.x == 0);
  float acc = 0.f;
  float ssl[8];
#pragma unroll
  for (int j = 0; j < 8; ++j) ssl[j] = 0.f;
  for (int kc = 0; kc < EE; kc += 64) {
#pragma unroll
    for (int j = 0; j < 8; ++j) {
      int i = tid + j * 256;
      int bb = i >> 6, k = i & 63;
      float v = h[bb * EE + kc + k];
      ssl[j] += v * v;
      Hs[bb][k] = v * bnw[kc + k];
      if (writer) {
        float d = v + initBias[kc + k];
        if (initAdd) d += initAdd[bb * EE + kc + k];
        initDst[bb * EE + kc + k] = d;
      }
    }
#pragma unroll
    for (int j = 0; j < 2; ++j) {
      int i = tid + j * 256;
      int cc = i >> 6, k = i & 63;
      Ws[cc][k] = W[(size_t)(col0 + cc) * EE + kc + k];
    }
    __syncthreads();
#pragma unroll
    for (int k = 0; k < 64; k += 4) {
      float4 w4 = *(const float4*)&Ws[c][k];
      float4 h4 = *(const float4*)&Hs[b][k];
      acc += h4.x * w4.x + h4.y * w4.y + h4.z * w4.z + h4.w * w4.w;
    }
    __syncthreads();
  }
  const int wv = tid >> 6;
#pragma unroll
  for (int j = 0; j < 8; ++j) {
    float v = ssl[j];
#pragma unroll
    for (int off = 32; off > 0; off >>= 1) v += __shfl_xor(v, off);
    if ((tid & 63) == 0) ssrow[wv + 4 * j] = v;
  }
  __syncthreads();
  float rinv = rsqrtf(ssrow[b] * (1.f / EE) + EPSF);
  float z = acc * rinv + bias[col0 + c];
  yout[b * MM + col0 + c] = z / (1.f + expf(-z));
}

__global__ __launch_bounds__(256)
void k_fc2(const float* __restrict__ y, const float* __restrict__ W2,
           float* __restrict__ dest) {
  __shared__ __align__(16) float Ys[32][68];
  __shared__ __align__(16) float Ws[16][68];
  const int tid = threadIdx.x;
  const int cgi = blockIdx.x & 63;
  const int ks = blockIdx.x >> 6;
  const int col0 = cgi * 16;
  const int c = tid & 15;
  const int bq = tid >> 4;
  float acc0 = 0.f, acc1 = 0.f;
  const int kend = ks * 512 + 512;
  for (int kc = ks * 512; kc < kend; kc += 64) {
#pragma unroll
    for (int j = 0; j < 8; ++j) {
      int i = tid + j * 256;
      int bb = i >> 6, k = i & 63;
      Ys[bb][k] = y[bb * MM + kc + k];
    }
#pragma unroll
    for (int j = 0; j < 4; ++j) {
      int i = tid + j * 256;
      int cc = i >> 6, k = i & 63;
      Ws[cc][k] = W2[(size_t)(col0 + cc) * MM + kc + k];
    }
    __syncthreads();
#pragma unroll
    for (int k = 0; k < 64; k += 4) {
      float4 w4 = *(const float4*)&Ws[c][k];
      float4 a4 = *(const float4*)&Ys[bq][k];
      float4 b4 = *(const float4*)&Ys[bq + 16][k];
      acc0 += a4.x * w4.x + a4.y * w4.y + a4.z * w4.z + a4.w * w4.w;
      acc1 += b4.x * w4.x + b4.y * w4.y + b4.z * w4.z + b4.w * w4.w;
    }
    __syncthreads();
  }
  atomicAdd(&dest[bq * EE + col0 + c], acc0);
  atomicAdd(&dest[(bq + 16) * EE + col0 + c], acc1);
}

__global__ __launch_bounds__(256)
void k_nxt(const float* __restrict__ s, const float* __restrict__ nw,
           const float* __restrict__ Wn, const float* __restrict__ nb,
           float* __restrict__ nxt_out, float* __restrict__ ss_out,
           const int* __restrict__ tokens, const float* __restrict__ embw,
           float* __restrict__ inp_next, int tnext) {
  __shared__ __align__(16) float Xs[32][68];
  __shared__ __align__(16) float Ws[8][68];
  __shared__ float ssrow[32];
  const int tid = threadIdx.x;
  const int col0 = blockIdx.x * 8;
  const int c = tid & 7;
  const int b = tid >> 3;
  float acc = 0.f;
  float ssl[8];
#pragma unroll
  for (int j = 0; j < 8; ++j) ssl[j] = 0.f;
  for (int kc = 0; kc < EE; kc += 64) {
#pragma unroll
    for (int j = 0; j < 8; ++j) {
      int i = tid + j * 256;
      int bb = i >> 6, k = i & 63;
      float v = s[bb * EE + kc + k];
      ssl[j] += v * v;
      Xs[bb][k] = v * nw[kc + k];
    }
#pragma unroll
    for (int j = 0; j < 2; ++j) {
      int i = tid + j * 256;
      int cc = i >> 6, k = i & 63;
      Ws[cc][k] = Wn[(size_t)(col0 + cc) * EE + kc + k];
    }
    __syncthreads();
#pragma unroll
    for (int k = 0; k < 64; k += 4) {
      float4 w4 = *(const float4*)&Ws[c][k];
      float4 h4 = *(const float4*)&Xs[b][k];
      acc += h4.x * w4.x + h4.y * w4.y + h4.z * w4.z + h4.w * w4.w;
    }
    __syncthreads();
  }
  const int wv = tid >> 6;
#pragma unroll
  for (int j = 0; j < 8; ++j) {
    float v = ssl[j];
#pragma unroll
    for (int off = 32; off > 0; off >>= 1) v += __shfl_xor(v, off);
    if ((tid & 63) == 0) {
      ssrow[wv + 4 * j] = v;
      if (blockIdx.x == 0) ss_out[wv + 4 * j] = v;
    }
  }
  __syncthreads();
  float rinv = rsqrtf(ssrow[b] * (1.f / EE) + EPSF);
  float nv = acc * rinv + nb[col0 + c];
  nxt_out[b * EE + col0 + c] = nv;
  if (inp_next) {
    int tok = tokens[b * TT + tnext];
    inp_next[b * EE + col0 + c] = embw[(size_t)tok * EE + col0 + c] + nv;
  }
}

// ======================= phase 2 =======================

__global__ __launch_bounds__(256)
void k_curemb(const float* __restrict__ s_all, const float* __restrict__ ss_s,
              const float* __restrict__ nw, const float* __restrict__ Wc,
              const float* __restrict__ cb, const float* __restrict__ inp_all,
              float* __restrict__ cur_out, float* __restrict__ aux_accum) {
  __shared__ __align__(16) float As[16][68];
  __shared__ __align__(16) float Bs[16][68];
  __shared__ float rr[64];
  __shared__ float wred[4];
  const int tid = threadIdx.x;
  const int rt = blockIdx.x & 127;
  const int ct = blockIdx.x >> 7;
  const int row0 = rt * 64, col0 = ct * 64;
  if (tid < 64) rr[tid] = rsqrtf(ss_s[row0 + tid] * (1.f / EE) + EPSF);
  __syncthreads();
  float acc[4][4];
#pragma unroll
  for (int i = 0; i < 4; ++i)
#pragma unroll
    for (int j = 0; j < 4; ++j) acc[i][j] = 0.f;
  const int tx = tid & 15, ty = tid >> 4;
  for (int kc = 0; kc < EE; kc += 16) {
#pragma unroll
    for (int j = 0; j < 4; ++j) {
      int i = tid + j * 256;
      int k = i & 15, m = i >> 4;
      As[k][m] = s_all[(size_t)(row0 + m) * EE + kc + k] * rr[m] * nw[kc + k];
      Bs[k][m] = Wc[(size_t)(col0 + m) * EE + kc + k];
    }
    __syncthreads();
#pragma unroll
    for (int k = 0; k < 16; ++k) {
      float4 a4 = *(const float4*)&As[k][tx * 4];
      float4 b4 = *(const float4*)&Bs[k][ty * 4];
      acc[0][0] += a4.x*b4.x; acc[0][1] += a4.x*b4.y; acc[0][2] += a4.x*b4.z; acc[0][3] += a4.x*b4.w;
      acc[1][0] += a4.y*b4.x; acc[1][1] += a4.y*b4.y; acc[1][2] += a4.y*b4.z; acc[1][3] += a4.y*b4.w;
      acc[2][0] += a4.z*b4.x; acc[2][1] += a4.z*b4.y; acc[2][2] += a4.z*b4.z; acc[2][3] += a4.z*b4.w;
      acc[3][0] += a4.w*b4.x; acc[3][1] += a4.w*b4.y; acc[3][2] += a4.w*b4.z; acc[3][3] += a4.w*b4.w;
    }
    __syncthreads();
  }
  float auxp = 0.f;
#pragma unroll
  for (int i = 0; i < 4; ++i) {
    int r = row0 + tx * 4 + i;
#pragma unroll
    for (int j = 0; j < 4; ++j) {
      int col = col0 + ty * 4 + j;
      float v = acc[i][j] + cb[col];
      cur_out[(size_t)r * EE + col] = v;
      float d = v - inp_all[(size_t)r * EE + col];
      auxp += d * d;
    }
  }
#pragma unroll
  for (int off = 32; off > 0; off >>= 1) auxp += __shfl_xor(auxp, off);
  if ((tid & 63) == 0) wred[tid >> 6] = auxp;
  __syncthreads();
  if (tid == 0) atomicAdd(aux_accum, wred[0] + wred[1] + wred[2] + wred[3]);
}

__global__ __launch_bounds__(256)
void k_logits(const float* __restrict__ A, const float* __restrict__ embw,
              const int* __restrict__ idxs, float* __restrict__ rowsum,
              float* __restrict__ lidx, float* __restrict__ store) {
  __shared__ __align__(16) float As[16][68];
  __shared__ __align__(16) float Bs[16][68];
  __shared__ float rowpart[64];
  const int tid = threadIdx.x;
  const int rt = blockIdx.x & 127;
  const int ct = blockIdx.x >> 7;
  const int row0 = rt * 64, col0 = ct * 64;
  float acc[4][4];
#pragma unroll
  for (int i = 0; i < 4; ++i)
#pragma unroll
    for (int j = 0; j < 4; ++j) acc[i][j] = 0.f;
  const int tx = tid & 15, ty = tid >> 4;
  for (int kc = 0; kc < EE; kc += 16) {
#pragma unroll
    for (int j = 0; j < 4; ++j) {
      int i = tid + j * 256;
      int k = i & 15, m = i >> 4;
      As[k][m] = A[(size_t)(row0 + m) * EE + kc + k];
      Bs[k][m] = embw[(size_t)(col0 + m) * EE + kc + k];
    }
    __syncthreads();
#pragma unroll
    for (int k = 0; k < 16; ++k) {
      float4 a4 = *(const float4*)&As[k][tx * 4];
      float4 b4 = *(const float4*)&Bs[k][ty * 4];
      acc[0][0] += a4.x*b4.x; acc[0][1] += a4.x*b4.y; acc[0][2] += a4.x*b4.z; acc[0][3] += a4.x*b4.w;
      acc[1][0] += a4.y*b4.x; acc[1][1] += a4.y*b4.y; acc[1][2] += a4.y*b4.z; acc[1][3] += a4.y*b4.w;
      acc[2][0] += a4.z*b4.x; acc[2][1] += a4.z*b4.y; acc[2][2] += a4.z*b4.z; acc[2][3] += a4.z*b4.w;
      acc[3][0] += a4.w*b4.x; acc[3][1] += a4.w*b4.y; acc[3][2] += a4.w*b4.z; acc[3][3] += a4.w*b4.w;
    }
    __syncthreads();
  }
  if (tid < 64) rowpart[tid] = 0.f;
  __syncthreads();
#pragma unroll
  for (int i = 0; i < 4; ++i) {
    int r = row0 + tx * 4 + i;
    int t = r >> 5, bb = r & 31;
    int idx = idxs[bb * TT + t];
    float e0 = expf(acc[i][0]);
    float e1 = expf(acc[i][1]);
    float e2 = expf(acc[i][2]);
    float e3 = expf(acc[i][3]);
    atomicAdd(&rowpart[tx * 4 + i], e0 + e1 + e2 + e3);
    int cbase = col0 + ty * 4;
#pragma unroll
    for (int j = 0; j < 4; ++j)
      if (cbase + j == idx) lidx[r] = acc[i][j];
    if (store) {
      float4 o = make_float4(acc[i][0], acc[i][1], acc[i][2], acc[i][3]);
      *(float4*)(store + ((size_t)bb * TT + t) * VV + cbase) = o;
    }
  }
  __syncthreads();
  if (tid < 64) atomicAdd(&rowsum[row0 + tid], rowpart[tid]);
}

__global__ void k_final(const float* __restrict__ rs_cur,
                        const float* __restrict__ rs_nxt,
                        const float* __restrict__ ltok,
                        const float* __restrict__ ltgt,
                        const float* __restrict__ aux_accum,
                        float* __restrict__ out) {
  float p = 0.f;
  for (int r = threadIdx.x; r < NROWS; r += 256)
    p += (ltok[r] - logf(rs_cur[r])) + (ltgt[r] - logf(rs_nxt[r]));
#pragma unroll
  for (int off = 32; off > 0; off >>= 1) p += __shfl_xor(p, off);
  __shared__ float w[4];
  if ((threadIdx.x & 63) == 0) w[threadIdx.x >> 6] = p;
  __syncthreads();
  if (threadIdx.x == 0) {
    float tot = w[0] + w[1] + w[2] + w[3];
    out[0] = -tot / (2.f * (float)NROWS);
    out[1] = aux_accum[0] * (1.f / ((float)NROWS * EE));
  }
}

// ======================= launch =======================

extern "C" void kernel_launch(void* const* d_in, const int* in_sizes, int n_in,
                              void* d_out, int out_size, void* d_ws, size_t ws_size,
                              hipStream_t stream) {
  (void)in_sizes; (void)n_in; (void)out_size; (void)ws_size;
  const int*   tokens  = (const int*)d_in[0];
  const int*   targets = (const int*)d_in[1];
  const float* embw    = (const float*)d_in[2];
  const float* bnw     = (const float*)d_in[3];
  const float* fc1w    = (const float*)d_in[4];
  const float* fc1b    = (const float*)d_in[5];
  const float* fc2w    = (const float*)d_in[6];
  const float* fc2b    = (const float*)d_in[7];
  const float* nw      = (const float*)d_in[8];
  const float* curw    = (const float*)d_in[9];
  const float* curb    = (const float*)d_in[10];
  const float* nxtw    = (const float*)d_in[11];
  const float* nxtb    = (const float*)d_in[12];
  float* out = (float*)d_out;

  // d_out doubles as scratch for three [8192][1024] fp32 activations; the
  // final logits GEMM overwrites all of it with the real output.
  float* cur_all = out;
  float* s_all   = out + (size_t)NROWS * EE;
  float* inp_all = out + 2 * (size_t)NROWS * EE;

  float* ws      = (float*)d_ws;
  float* nxt_all = ws;                                  // 8,388,608
  float* ybuf    = nxt_all + (size_t)NROWS * EE;        // 131,072 (fp32 / fp16 union)
  float* hbuf    = ybuf + 131072;                       // 32,768
  float* ssA     = hbuf + BE;                           // 257*32 = 8,224
  float* ssH     = ssA + 8224;                          // 8,192
  float* ssS     = ssH + 8192;                          // 8,192
  float* rs_cur  = ssS + 8192;                          // 8,192
  float* rs_nxt  = rs_cur + NROWS;                      // 8,192
  float* auxac   = rs_nxt + NROWS;                      // 1
  float* ltok    = auxac + 1;                           // 8,192
  float* ltgt    = ltok + NROWS;                        // 8,192
  // barrier counters, 128B aligned region
  unsigned* gcnt = (unsigned*)(ws + 8609856);           // 1280*8*32
  unsigned* mcnt = gcnt + 1280 * 8 * 32;                // 1280*32

  // zero: ssA..auxac plus counters (span ssA .. end of mcnt)
  const int nzero = (8609856 + 1280 * 8 * 32 + 1280 * 32) - 8552448;
  k_zero<<<(nzero + 255) / 256, 256, 0, stream>>>(ssA, nzero);
  k_init2<<<32, 256, 0, stream>>>(tokens, embw, inp_all, ssA);

  Scan3Params p;
  p.tokens = tokens; p.embw = embw; p.bnw = bnw;
  p.fc1w = fc1w; p.fc1b = fc1b; p.fc2w = fc2w; p.fc2b = fc2b;
  p.nw = nw; p.nxtw = nxtw; p.nxtb = nxtb;
  p.inp_all = inp_all; p.s_all = s_all; p.nxt_all = nxt_all;
  p.yh = (_Float16*)ybuf; p.hbuf = hbuf;
  p.ssA = ssA; p.ssH = ssH; p.ssS = ssS;
  p.gcnt = gcnt; p.mcnt = mcnt;

  const size_t shmem = 156800;
  hipError_t err = hipFuncSetAttribute((const void*)k_scan3,
      hipFuncAttributeMaxDynamicSharedMemorySize, (int)shmem);
  if (err == hipSuccess) {
    void* args[] = { &p };
    err = hipLaunchCooperativeKernel((const void*)k_scan3, dim3(256), dim3(512),
                                     args, shmem, stream);
  }
  if (err != hipSuccess) {
    // Fallback: proven round-1 multi-kernel sequence (fp32 throughout).
    for (int t = 0; t < TT; ++t) {
      const float* inp = inp_all + (size_t)t * BE;
      float* s = s_all + (size_t)t * BE;
      k_fc1<<<512, 256, 0, stream>>>(inp, bnw, fc1w, fc1b, ybuf,
                                     hbuf, nullptr, fc2b);
      k_fc2<<<512, 256, 0, stream>>>(ybuf, fc2w, hbuf);
      k_fc1<<<512, 256, 0, stream>>>(hbuf, bnw + EE, fc1w + (size_t)MM * EE,
                                     fc1b + MM, ybuf, s, inp, fc2b + EE);
      k_fc2<<<512, 256, 0, stream>>>(ybuf, fc2w + (size_t)EE * MM, s);
      k_nxt<<<128, 256, 0, stream>>>(s, nw, nxtw, nxtb,
                                     nxt_all + (size_t)t * BE, ssS + t * BB,
                                     tokens, embw,
                                     (t + 1 < TT) ? inp_all + (size_t)(t + 1) * BE : nullptr,
                                     t + 1);
    }
  }

  k_curemb<<<2048, 256, 0, stream>>>(s_all, ssS, nw, curw, curb, inp_all,
                                     cur_all, auxac);
  k_logits<<<8192, 256, 0, stream>>>(cur_all, embw, tokens, rs_cur, ltok, nullptr);
  k_logits<<<8192, 256, 0, stream>>>(nxt_all, embw, targets, rs_nxt, ltgt, out);
  k_final<<<1, 256, 0, stream>>>(rs_cur, rs_nxt, ltok, ltgt, auxac,
                                 out + (size_t)NROWS * VV);
}

// Round 7
// 19412.230 us; speedup vs baseline: 17.3935x; 1.6293x over previous
//
#include <hip/hip_runtime.h>
#include <math.h>

#define TT  256
#define BB  32
#define EE  1024
#define MM  4096
#define VV  4096
#define BE  (BB*EE)
#define NROWS (TT*BB)
#define EPSF 1.1920929e-07f

typedef _Float16 h2 __attribute__((ext_vector_type(2)));

__device__ inline float dot2f(h2 a, h2 b, float c) {
#if __has_builtin(__builtin_amdgcn_fdot2)
  return __builtin_amdgcn_fdot2(a, b, c, false);
#else
  return c + (float)a[0] * (float)b[0] + (float)a[1] * (float)b[1];
#endif
}

// ---- coherent-point (MALL) data movement: relaxed agent atomics = sc1 bypass ----
__device__ inline unsigned ldb_u32(const unsigned* p) {
  return __hip_atomic_load((unsigned*)p, __ATOMIC_RELAXED, __HIP_MEMORY_SCOPE_AGENT);
}
__device__ inline void stb_u32(unsigned* p, unsigned v) {
  __hip_atomic_store(p, v, __ATOMIC_RELAXED, __HIP_MEMORY_SCOPE_AGENT);
}
__device__ inline void stb_f32(float* p, float v) {
  __hip_atomic_store(p, v, __ATOMIC_RELAXED, __HIP_MEMORY_SCOPE_AGENT);
}

// ---- fence-free hierarchical grid barrier (fresh counters per barrier) ----
// Safe without fences: __syncthreads drains vmcnt(0) (all block stores complete
// at MALL, since cross-block data uses sc1/atomic ops), then a relaxed arrive;
// consumers' cached reads target per-t fresh addresses (first cached touch
// after the write; L2s invalidated at dispatch).
__device__ inline void gbar4(unsigned* cnt, int sidx) {
  __syncthreads();
  if (threadIdx.x == 0) {
    unsigned* base = cnt + (size_t)sidx * 17 * 32;
    unsigned* gp = base + (blockIdx.x & 15) * 32;
    unsigned* mp = base + 16 * 32;
    unsigned old = __hip_atomic_fetch_add(gp, 1u, __ATOMIC_RELAXED,
                                          __HIP_MEMORY_SCOPE_AGENT);
    if (old == 15u)
      __hip_atomic_fetch_add(mp, 1u, __ATOMIC_RELAXED, __HIP_MEMORY_SCOPE_AGENT);
    while (__hip_atomic_load(mp, __ATOMIC_RELAXED, __HIP_MEMORY_SCOPE_AGENT) < 16u)
      __builtin_amdgcn_s_sleep(1);
  }
  __syncthreads();
}

// ---- fc1-like stage: full-K, self-normalizing (rinv applied post-dot) ----
// src f32 [32][EE] cached; staged as (src*scl) fp16; ssacc per row during
// staging. NR output cols per block. Optional seeding (blocks 0-3, 2 chunks ea).
template<int NR>
__device__ float fc1like(int tid, int cu,
    const float* __restrict__ src, const float* __restrict__ scl,
    const h2* __restrict__ wl, h2* __restrict__ xs, float* __restrict__ red,
    float* __restrict__ ssrow,
    float* __restrict__ seedDst, const float* __restrict__ seedAdd,
    const float* __restrict__ seedBias) {
  const int b = tid & 31, kq = tid >> 5;
  const int sb = tid >> 4, se = (tid & 15) * 8;
  const int ep0 = (tid & 15) * 4;
  float ssacc = 0.f;
  float acc[NR];
#pragma unroll
  for (int m = 0; m < NR; ++m) acc[m] = 0.f;
  const bool seeder = (seedDst != nullptr) && (cu < 4);

  float4 v0, v1, c0v, c1v;
  auto ldchunk = [&](int c) {
    v0 = *(const float4*)&src[sb * EE + c * 128 + se];
    v1 = *(const float4*)&src[sb * EE + c * 128 + se + 4];
    c0v = *(const float4*)&scl[c * 128 + se];
    c1v = *(const float4*)&scl[c * 128 + se + 4];
  };
  auto flush = [&](int c) {
    h2* dst = xs + (c & 1) * (64 * 33);
    ssacc += v0.x*v0.x + v0.y*v0.y + v0.z*v0.z + v0.w*v0.w
           + v1.x*v1.x + v1.y*v1.y + v1.z*v1.z + v1.w*v1.w;
    h2 p0, p1, p2, p3;
    p0[0]=(_Float16)(v0.x*c0v.x); p0[1]=(_Float16)(v0.y*c0v.y);
    p1[0]=(_Float16)(v0.z*c0v.z); p1[1]=(_Float16)(v0.w*c0v.w);
    p2[0]=(_Float16)(v1.x*c1v.x); p2[1]=(_Float16)(v1.y*c1v.y);
    p3[0]=(_Float16)(v1.z*c1v.z); p3[1]=(_Float16)(v1.w*c1v.w);
    dst[(ep0+0)*33+sb]=p0; dst[(ep0+1)*33+sb]=p1;
    dst[(ep0+2)*33+sb]=p2; dst[(ep0+3)*33+sb]=p3;
    if (seeder && (c >> 1) == cu) {
      int e0 = c * 128 + se;
      float sv[8] = {v0.x,v0.y,v0.z,v0.w,v1.x,v1.y,v1.z,v1.w};
#pragma unroll
      for (int j = 0; j < 8; ++j) {
        float d = sv[j] + seedBias[e0 + j];
        if (seedAdd) d += seedAdd[sb * EE + e0 + j];
        stb_f32(&seedDst[sb * EE + e0 + j], d);
      }
    }
  };
  ldchunk(0); flush(0);
  __syncthreads();
  for (int c = 0; c < 8; ++c) {
    if (c < 7) ldchunk(c + 1);
    const h2* xb = xs + (c & 1) * (64 * 33);
    h2 x0 = xb[(kq*4+0)*33+b], x1 = xb[(kq*4+1)*33+b],
       x2 = xb[(kq*4+2)*33+b], x3 = xb[(kq*4+3)*33+b];
#pragma unroll
    for (int m = 0; m < NR; ++m) {
      const h2* wp = &wl[m * 512 + c * 64 + kq * 4];
      float a = acc[m];
      a = dot2f(x0, wp[0], a); a = dot2f(x1, wp[1], a);
      a = dot2f(x2, wp[2], a); a = dot2f(x3, wp[3], a);
      acc[m] = a;
    }
    if (c < 7) flush(c + 1);
    __syncthreads();
  }
  ssacc += __shfl_xor(ssacc, 8);
  ssacc += __shfl_xor(ssacc, 4);
  ssacc += __shfl_xor(ssacc, 2);
  ssacc += __shfl_xor(ssacc, 1);
  if ((tid & 15) == 0) ssrow[sb] = ssacc;
#pragma unroll
  for (int m = 0; m < NR; ++m) acc[m] += __shfl_xor(acc[m], 32);
  const int wv = tid >> 6, ln = tid & 63;
  if (ln < 32) {
#pragma unroll
    for (int m = 0; m < NR; ++m) red[wv * 544 + ln * 17 + m] = acc[m];
  }
  __syncthreads();
  float z = 0.f;
  if (tid < 32 * NR) {
    const int b2 = (NR == 16) ? (tid >> 4) : (tid >> 2);
    const int m2 = tid & (NR - 1);
#pragma unroll
    for (int w = 0; w < 8; ++w) z += red[w * 544 + b2 * 17 + m2];
  }
  return z;
}

// ---- fc2-like stage: K-slice 1024, NR=16 cols; y read via sc1 bypass ----
__device__ float fc2like(int tid,
    const unsigned* __restrict__ ysrc,   // base incl. k-slice offset; row stride MM/2
    const h2* __restrict__ wl, h2* __restrict__ xs, float* __restrict__ red) {
  const int b = tid & 31, kq = tid >> 5;
  const int sb = tid >> 4;
  const int ep0 = (tid & 15) * 4;
  float acc[16];
#pragma unroll
  for (int m = 0; m < 16; ++m) acc[m] = 0.f;
  unsigned q0, q1, q2, q3;
  auto ldchunk = [&](int c) {
    const unsigned* sp = ysrc + (size_t)sb * (MM / 2) + c * 64 + ep0;
    q0 = ldb_u32(sp + 0); q1 = ldb_u32(sp + 1);
    q2 = ldb_u32(sp + 2); q3 = ldb_u32(sp + 3);
  };
  auto flush = [&](int c) {
    h2* dst = xs + (c & 1) * (64 * 33);
    dst[(ep0+0)*33+sb] = __builtin_bit_cast(h2, q0);
    dst[(ep0+1)*33+sb] = __builtin_bit_cast(h2, q1);
    dst[(ep0+2)*33+sb] = __builtin_bit_cast(h2, q2);
    dst[(ep0+3)*33+sb] = __builtin_bit_cast(h2, q3);
  };
  ldchunk(0); flush(0);
  __syncthreads();
  for (int c = 0; c < 8; ++c) {
    if (c < 7) ldchunk(c + 1);
    const h2* xb = xs + (c & 1) * (64 * 33);
    h2 x0 = xb[(kq*4+0)*33+b], x1 = xb[(kq*4+1)*33+b],
       x2 = xb[(kq*4+2)*33+b], x3 = xb[(kq*4+3)*33+b];
#pragma unroll
    for (int m = 0; m < 16; ++m) {
      const h2* wp = &wl[m * 512 + c * 64 + kq * 4];
      float a = acc[m];
      a = dot2f(x0, wp[0], a); a = dot2f(x1, wp[1], a);
      a = dot2f(x2, wp[2], a); a = dot2f(x3, wp[3], a);
      acc[m] = a;
    }
    if (c < 7) flush(c + 1);
    __syncthreads();
  }
#pragma unroll
  for (int m = 0; m < 16; ++m) acc[m] += __shfl_xor(acc[m], 32);
  const int wv = tid >> 6, ln = tid & 63;
  if (ln < 32) {
#pragma unroll
    for (int m = 0; m < 16; ++m) red[wv * 544 + ln * 17 + m] = acc[m];
  }
  __syncthreads();
  const int b2 = tid >> 4, m2 = tid & 15;
  float z = 0.f;
#pragma unroll
  for (int w = 0; w < 8; ++w) z += red[w * 544 + b2 * 17 + m2];
  return z;
}

struct Scan4Params {
  const int* tokens; const float* embw;
  const float* bnw; const float* fc1w; const float* fc1b;
  const float* fc2w; const float* fc2b;
  const float* nw; const float* nxtw; const float* nxtb;
  float* inp_all;   // [TT][32][EE] (d_out q3)
  float* s_all;     // [TT][32][EE] (d_out q2)
  float* hbuf_all;  // [TT][32][EE] (d_out q4)
  float* nxt_all;   // [TT][32][EE] (ws)
  unsigned* yh;     // [32][MM/2] fp16 pairs (ws)
  float* ssS;       // [TT][32]
  unsigned* cnt;    // barrier counters
};

__global__ __launch_bounds__(512, 1) void k_scan4(Scan4Params p) {
  extern __shared__ __align__(16) char smem[];
  h2* w1a = (h2*)smem;                      // [16][512]
  h2* w1b = (h2*)(smem + 32768);
  h2* w2a = (h2*)(smem + 65536);            // [16][512] (K-slice)
  h2* w2b = (h2*)(smem + 98304);
  h2* wn  = (h2*)(smem + 131072);           // [4][512]
  h2* xs  = (h2*)(smem + 139264);           // 2x[64][33] h2, red overlay
  float* red = (float*)(smem + 139264);
  float* ssrow = (float*)(smem + 156672);   // [32]
  const int tid = threadIdx.x;
  const int cu = blockIdx.x;
  const int cg = cu & 63, ks = cu >> 6;

  // one-time: stage this block's weight slices fp32 -> fp16 LDS
#pragma unroll 4
  for (int r = 0; r < 16; ++r) {
    float2 f = *(const float2*)&p.fc1w[(size_t)(cu * 16 + r) * EE + tid * 2];
    h2 h; h[0] = (_Float16)f.x; h[1] = (_Float16)f.y;
    w1a[r * 512 + tid] = h;
    float2 g = *(const float2*)&p.fc1w[(size_t)MM * EE +
                                       (size_t)(cu * 16 + r) * EE + tid * 2];
    h2 hb; hb[0] = (_Float16)g.x; hb[1] = (_Float16)g.y;
    w1b[r * 512 + tid] = hb;
    float2 a = *(const float2*)&p.fc2w[(size_t)(cg * 16 + r) * MM +
                                       ks * 1024 + tid * 2];
    h2 ha; ha[0] = (_Float16)a.x; ha[1] = (_Float16)a.y;
    w2a[r * 512 + tid] = ha;
    float2 bb = *(const float2*)&p.fc2w[(size_t)EE * MM +
                                        (size_t)(cg * 16 + r) * MM +
                                        ks * 1024 + tid * 2];
    h2 hc; hc[0] = (_Float16)bb.x; hc[1] = (_Float16)bb.y;
    w2b[r * 512 + tid] = hc;
  }
#pragma unroll
  for (int r = 0; r < 4; ++r) {
    float2 f = *(const float2*)&p.nxtw[(size_t)(cu * 4 + r) * EE + tid * 2];
    h2 h; h[0] = (_Float16)f.x; h[1] = (_Float16)f.y;
    wn[r * 512 + tid] = h;
  }
  __syncthreads();

  int sidx = 0;
  for (int t = 0; t < TT; ++t) {
    const float* inp = p.inp_all + (size_t)t * BE;
    float* hb = p.hbuf_all + (size_t)t * BE;
    float* st = p.s_all + (size_t)t * BE;

    // A: y0 = silu(rms(inp)@w1a + b); seeds hbuf = inp + fc2b0
    {
      float z = fc1like<16>(tid, cu, inp, p.bnw, w1a, xs, red, ssrow,
                            hb, nullptr, p.fc2b);
      const int b2 = tid >> 4, m2 = tid & 15, gm = cu * 16 + m2;
      float rinv = rsqrtf(ssrow[b2] * (1.f / EE) + EPSF);
      float zz = z * rinv + p.fc1b[gm];
      float yv = zz / (1.f + expf(-zz));
      unsigned bits = (unsigned)__builtin_bit_cast(unsigned short, (_Float16)yv);
      unsigned other = __shfl_xor(bits, 1);
      if ((tid & 1) == 0)
        stb_u32(&p.yh[b2 * (MM / 2) + (gm >> 1)], bits | (other << 16));
    }
    gbar4(p.cnt, sidx++);
    // B: hbuf += y0-slice @ w2a-slice (K-split partials)
    {
      float z = fc2like(tid, p.yh + ks * 512, w2a, xs, red);
      atomicAdd(&hb[(tid >> 4) * EE + cg * 16 + (tid & 15)], z);
    }
    gbar4(p.cnt, sidx++);
    // C: y1 = silu(rms(h)@w1b + b); seeds s = h + inp + fc2b1
    {
      float z = fc1like<16>(tid, cu, hb, p.bnw + EE, w1b, xs, red, ssrow,
                            st, inp, p.fc2b + EE);
      const int b2 = tid >> 4, m2 = tid & 15, gm = cu * 16 + m2;
      float rinv = rsqrtf(ssrow[b2] * (1.f / EE) + EPSF);
      float zz = z * rinv + p.fc1b[MM + gm];
      float yv = zz / (1.f + expf(-zz));
      unsigned bits = (unsigned)__builtin_bit_cast(unsigned short, (_Float16)yv);
      unsigned other = __shfl_xor(bits, 1);
      if ((tid & 1) == 0)
        stb_u32(&p.yh[b2 * (MM / 2) + (gm >> 1)], bits | (other << 16));
    }
    gbar4(p.cnt, sidx++);
    // D: s += y1-slice @ w2b-slice
    {
      float z = fc2like(tid, p.yh + ks * 512, w2b, xs, red);
      atomicAdd(&st[(tid >> 4) * EE + cg * 16 + (tid & 15)], z);
    }
    gbar4(p.cnt, sidx++);
    // E: nxt = rms(s)@wn + nb; carry inp_{t+1}; persist ssS
    {
      float z = fc1like<4>(tid, cu, st, p.nw, wn, xs, red, ssrow,
                           nullptr, nullptr, nullptr);
      if (cu == 0 && tid < 32) p.ssS[t * 32 + tid] = ssrow[tid];
      if (tid < 128) {
        const int b2 = tid >> 2, m2 = tid & 3, gn = cu * 4 + m2;
        float rinv = rsqrtf(ssrow[b2] * (1.f / EE) + EPSF);
        float nv = z * rinv + p.nxtb[gn];
        stb_f32(&p.nxt_all[(size_t)t * BE + b2 * EE + gn], nv);
        if (t + 1 < TT) {
          int tok = p.tokens[b2 * TT + t + 1];
          stb_f32(&p.inp_all[(size_t)(t + 1) * BE + b2 * EE + gn],
                  p.embw[(size_t)tok * EE + gn] + nv);
        }
      }
    }
    gbar4(p.cnt, sidx++);
  }
}

// ======================= helpers =======================

__global__ void k_zero(float* __restrict__ p, int n) {
  int i = blockIdx.x * 256 + threadIdx.x;
  if (i < n) p[i] = 0.f;
}

__global__ void k_init(const int* __restrict__ tokens,
                       const float* __restrict__ embw,
                       float* __restrict__ inp0) {
  int b = blockIdx.x;
  int tok = tokens[b * TT];
  int e = threadIdx.x * 4;
  float4 v = *(const float4*)&embw[(size_t)tok * EE + e];
  *(float4*)&inp0[b * EE + e] = v;
}

// ======================= legacy fallback (round-1, proven) =======================

__global__ __launch_bounds__(256)
void k_fc1(const float* __restrict__ h, const float* __restrict__ bnw,
           const float* __restrict__ W, const float* __restrict__ bias,
           float* __restrict__ yout, float* __restrict__ initDst,
           const float* __restrict__ initAdd, const float* __restrict__ initBias) {
  __shared__ __align__(16) float Hs[32][68];
  __shared__ __align__(16) float Ws[8][68];
  __shared__ float ssrow[32];
  const int tid = threadIdx.x;
  const int col0 = blockIdx.x * 8;
  const int c = tid & 7;
  const int b = tid >> 3;
  const bool writer = (blockIdx.x == 0);
  float acc = 0.f;
  float ssl[8];
#pragma unroll
  for (int j = 0; j < 8; ++j) ssl[j] = 0.f;
  for (int kc = 0; kc < EE; kc += 64) {
#pragma unroll
    for (int j = 0; j < 8; ++j) {
      int i = tid + j * 256;
      int bb = i >> 6, k = i & 63;
      float v = h[bb * EE + kc + k];
      ssl[j] += v * v;
      Hs[bb][k] = v * bnw[kc + k];
      if (writer) {
        float d = v + initBias[kc + k];
        if (initAdd) d += initAdd[bb * EE + kc + k];
        initDst[bb * EE + kc + k] = d;
      }
    }
#pragma unroll
    for (int j = 0; j < 2; ++j) {
      int i = tid + j * 256;
      int cc = i >> 6, k = i & 63;
      Ws[cc][k] = W[(size_t)(col0 + cc) * EE + kc + k];
    }
    __syncthreads();
#pragma unroll
    for (int k = 0; k < 64; k += 4) {
      float4 w4 = *(const float4*)&Ws[c][k];
      float4 h4 = *(const float4*)&Hs[b][k];
      acc += h4.x * w4.x + h4.y * w4.y + h4.z * w4.z + h4.w * w4.w;
    }
    __syncthreads();
  }
  const int wv = tid >> 6;
#pragma unroll
  for (int j = 0; j < 8; ++j) {
    float v = ssl[j];
#pragma unroll
    for (int off = 32; off > 0; off >>= 1) v += __shfl_xor(v, off);
    if ((tid & 63) == 0) ssrow[wv + 4 * j] = v;
  }
  __syncthreads();
  float rinv = rsqrtf(ssrow[b] * (1.f / EE) + EPSF);
  float z = acc * rinv + bias[col0 + c];
  yout[b * MM + col0 + c] = z / (1.f + expf(-z));
}

__global__ __launch_bounds__(256)
void k_fc2(const float* __restrict__ y, const float* __restrict__ W2,
           float* __restrict__ dest) {
  __shared__ __align__(16) float Ys[32][68];
  __shared__ __align__(16) float Ws[16][68];
  const int tid = threadIdx.x;
  const int cgi = blockIdx.x & 63;
  const int ks = blockIdx.x >> 6;
  const int col0 = cgi * 16;
  const int c = tid & 15;
  const int bq = tid >> 4;
  float acc0 = 0.f, acc1 = 0.f;
  const int kend = ks * 512 + 512;
  for (int kc = ks * 512; kc < kend; kc += 64) {
#pragma unroll
    for (int j = 0; j < 8; ++j) {
      int i = tid + j * 256;
      int bb = i >> 6, k = i & 63;
      Ys[bb][k] = y[bb * MM + kc + k];
    }
#pragma unroll
    for (int j = 0; j < 4; ++j) {
      int i = tid + j * 256;
      int cc = i >> 6, k = i & 63;
      Ws[cc][k] = W2[(size_t)(col0 + cc) * MM + kc + k];
    }
    __syncthreads();
#pragma unroll
    for (int k = 0; k < 64; k += 4) {
      float4 w4 = *(const float4*)&Ws[c][k];
      float4 a4 = *(const float4*)&Ys[bq][k];
      float4 b4 = *(const float4*)&Ys[bq + 16][k];
      acc0 += a4.x * w4.x + a4.y * w4.y + a4.z * w4.z + a4.w * w4.w;
      acc1 += b4.x * w4.x + b4.y * w4.y + b4.z * w4.z + b4.w * w4.w;
    }
    __syncthreads();
  }
  atomicAdd(&dest[bq * EE + col0 + c], acc0);
  atomicAdd(&dest[(bq + 16) * EE + col0 + c], acc1);
}

__global__ __launch_bounds__(256)
void k_nxt(const float* __restrict__ s, const float* __restrict__ nw,
           const float* __restrict__ Wn, const float* __restrict__ nb,
           float* __restrict__ nxt_out, float* __restrict__ ss_out,
           const int* __restrict__ tokens, const float* __restrict__ embw,
           float* __restrict__ inp_next, int tnext) {
  __shared__ __align__(16) float Xs[32][68];
  __shared__ __align__(16) float Ws[8][68];
  __shared__ float ssrow[32];
  const int tid = threadIdx.x;
  const int col0 = blockIdx.x * 8;
  const int c = tid & 7;
  const int b = tid >> 3;
  float acc = 0.f;
  float ssl[8];
#pragma unroll
  for (int j = 0; j < 8; ++j) ssl[j] = 0.f;
  for (int kc = 0; kc < EE; kc += 64) {
#pragma unroll
    for (int j = 0; j < 8; ++j) {
      int i = tid + j * 256;
      int bb = i >> 6, k = i & 63;
      float v = s[bb * EE + kc + k];
      ssl[j] += v * v;
      Xs[bb][k] = v * nw[kc + k];
    }
#pragma unroll
    for (int j = 0; j < 2; ++j) {
      int i = tid + j * 256;
      int cc = i >> 6, k = i & 63;
      Ws[cc][k] = Wn[(size_t)(col0 + cc) * EE + kc + k];
    }
    __syncthreads();
#pragma unroll
    for (int k = 0; k < 64; k += 4) {
      float4 w4 = *(const float4*)&Ws[c][k];
      float4 h4 = *(const float4*)&Xs[b][k];
      acc += h4.x * w4.x + h4.y * w4.y + h4.z * w4.z + h4.w * w4.w;
    }
    __syncthreads();
  }
  const int wv = tid >> 6;
#pragma unroll
  for (int j = 0; j < 8; ++j) {
    float v = ssl[j];
#pragma unroll
    for (int off = 32; off > 0; off >>= 1) v += __shfl_xor(v, off);
    if ((tid & 63) == 0) {
      ssrow[wv + 4 * j] = v;
      if (blockIdx.x == 0) ss_out[wv + 4 * j] = v;
    }
  }
  __syncthreads();
  float rinv = rsqrtf(ssrow[b] * (1.f / EE) + EPSF);
  float nv = acc * rinv + nb[col0 + c];
  nxt_out[b * EE + col0 + c] = nv;
  if (inp_next) {
    int tok = tokens[b * TT + tnext];
    inp_next[b * EE + col0 + c] = embw[(size_t)tok * EE + col0 + c] + nv;
  }
}

// ======================= phase 2 =======================

__global__ __launch_bounds__(256)
void k_curemb(const float* __restrict__ s_all, const float* __restrict__ ss_s,
              const float* __restrict__ nw, const float* __restrict__ Wc,
              const float* __restrict__ cb, const float* __restrict__ inp_all,
              float* __restrict__ cur_out, float* __restrict__ aux_accum) {
  __shared__ __align__(16) float As[16][68];
  __shared__ __align__(16) float Bs[16][68];
  __shared__ float rr[64];
  __shared__ float wred[4];
  const int tid = threadIdx.x;
  const int rt = blockIdx.x & 127;
  const int ct = blockIdx.x >> 7;
  const int row0 = rt * 64, col0 = ct * 64;
  if (tid < 64) rr[tid] = rsqrtf(ss_s[row0 + tid] * (1.f / EE) + EPSF);
  __syncthreads();
  float acc[4][4];
#pragma unroll
  for (int i = 0; i < 4; ++i)
#pragma unroll
    for (int j = 0; j < 4; ++j) acc[i][j] = 0.f;
  const int tx = tid & 15, ty = tid >> 4;
  for (int kc = 0; kc < EE; kc += 16) {
#pragma unroll
    for (int j = 0; j < 4; ++j) {
      int i = tid + j * 256;
      int k = i & 15, m = i >> 4;
      As[k][m] = s_all[(size_t)(row0 + m) * EE + kc + k] * rr[m] * nw[kc + k];
      Bs[k][m] = Wc[(size_t)(col0 + m) * EE + kc + k];
    }
    __syncthreads();
#pragma unroll
    for (int k = 0; k < 16; ++k) {
      float4 a4 = *(const float4*)&As[k][tx * 4];
      float4 b4 = *(const float4*)&Bs[k][ty * 4];
      acc[0][0] += a4.x*b4.x; acc[0][1] += a4.x*b4.y; acc[0][2] += a4.x*b4.z; acc[0][3] += a4.x*b4.w;
      acc[1][0] += a4.y*b4.x; acc[1][1] += a4.y*b4.y; acc[1][2] += a4.y*b4.z; acc[1][3] += a4.y*b4.w;
      acc[2][0] += a4.z*b4.x; acc[2][1] += a4.z*b4.y; acc[2][2] += a4.z*b4.z; acc[2][3] += a4.z*b4.w;
      acc[3][0] += a4.w*b4.x; acc[3][1] += a4.w*b4.y; acc[3][2] += a4.w*b4.z; acc[3][3] += a4.w*b4.w;
    }
    __syncthreads();
  }
  float auxp = 0.f;
#pragma unroll
  for (int i = 0; i < 4; ++i) {
    int r = row0 + tx * 4 + i;
#pragma unroll
    for (int j = 0; j < 4; ++j) {
      int col = col0 + ty * 4 + j;
      float v = acc[i][j] + cb[col];
      cur_out[(size_t)r * EE + col] = v;
      float d = v - inp_all[(size_t)r * EE + col];
      auxp += d * d;
    }
  }
#pragma unroll
  for (int off = 32; off > 0; off >>= 1) auxp += __shfl_xor(auxp, off);
  if ((tid & 63) == 0) wred[tid >> 6] = auxp;
  __syncthreads();
  if (tid == 0) atomicAdd(aux_accum, wred[0] + wred[1] + wred[2] + wred[3]);
}

__global__ __launch_bounds__(256)
void k_logits(const float* __restrict__ A, const float* __restrict__ embw,
              const int* __restrict__ idxs, float* __restrict__ rowsum,
              float* __restrict__ lidx, float* __restrict__ store) {
  __shared__ __align__(16) float As[16][68];
  __shared__ __align__(16) float Bs[16][68];
  __shared__ float rowpart[64];
  const int tid = threadIdx.x;
  const int rt = blockIdx.x & 127;
  const int ct = blockIdx.x >> 7;
  const int row0 = rt * 64, col0 = ct * 64;
  float acc[4][4];
#pragma unroll
  for (int i = 0; i < 4; ++i)
#pragma unroll
    for (int j = 0; j < 4; ++j) acc[i][j] = 0.f;
  const int tx = tid & 15, ty = tid >> 4;
  for (int kc = 0; kc < EE; kc += 16) {
#pragma unroll
    for (int j = 0; j < 4; ++j) {
      int i = tid + j * 256;
      int k = i & 15, m = i >> 4;
      As[k][m] = A[(size_t)(row0 + m) * EE + kc + k];
      Bs[k][m] = embw[(size_t)(col0 + m) * EE + kc + k];
    }
    __syncthreads();
#pragma unroll
    for (int k = 0; k < 16; ++k) {
      float4 a4 = *(const float4*)&As[k][tx * 4];
      float4 b4 = *(const float4*)&Bs[k][ty * 4];
      acc[0][0] += a4.x*b4.x; acc[0][1] += a4.x*b4.y; acc[0][2] += a4.x*b4.z; acc[0][3] += a4.x*b4.w;
      acc[1][0] += a4.y*b4.x; acc[1][1] += a4.y*b4.y; acc[1][2] += a4.y*b4.z; acc[1][3] += a4.y*b4.w;
      acc[2][0] += a4.z*b4.x; acc[2][1] += a4.z*b4.y; acc[2][2] += a4.z*b4.z; acc[2][3] += a4.z*b4.w;
      acc[3][0] += a4.w*b4.x; acc[3][1] += a4.w*b4.y; acc[3][2] += a4.w*b4.z; acc[3][3] += a4.w*b4.w;
    }
    __syncthreads();
  }
  if (tid < 64) rowpart[tid] = 0.f;
  __syncthreads();
#pragma unroll
  for (int i = 0; i < 4; ++i) {
    int r = row0 + tx * 4 + i;
    int t = r >> 5, bb = r & 31;
    int idx = idxs[bb * TT + t];
    float e0 = expf(acc[i][0]);
    float e1 = expf(acc[i][1]);
    float e2 = expf(acc[i][2]);
    float e3 = expf(acc[i][3]);
    atomicAdd(&rowpart[tx * 4 + i], e0 + e1 + e2 + e3);
    int cbase = col0 + ty * 4;
#pragma unroll
    for (int j = 0; j < 4; ++j)
      if (cbase + j == idx) lidx[r] = acc[i][j];
    if (store) {
      float4 o = make_float4(acc[i][0], acc[i][1], acc[i][2], acc[i][3]);
      *(float4*)(store + ((size_t)bb * TT + t) * VV + cbase) = o;
    }
  }
  __syncthreads();
  if (tid < 64) atomicAdd(&rowsum[row0 + tid], rowpart[tid]);
}

__global__ void k_final(const float* __restrict__ rs_cur,
                        const float* __restrict__ rs_nxt,
                        const float* __restrict__ ltok,
                        const float* __restrict__ ltgt,
                        const float* __restrict__ aux_accum,
                        float* __restrict__ out) {
  float p = 0.f;
  for (int r = threadIdx.x; r < NROWS; r += 256)
    p += (ltok[r] - logf(rs_cur[r])) + (ltgt[r] - logf(rs_nxt[r]));
#pragma unroll
  for (int off = 32; off > 0; off >>= 1) p += __shfl_xor(p, off);
  __shared__ float w[4];
  if ((threadIdx.x & 63) == 0) w[threadIdx.x >> 6] = p;
  __syncthreads();
  if (threadIdx.x == 0) {
    float tot = w[0] + w[1] + w[2] + w[3];
    out[0] = -tot / (2.f * (float)NROWS);
    out[1] = aux_accum[0] * (1.f / ((float)NROWS * EE));
  }
}

// ======================= launch =======================

extern "C" void kernel_launch(void* const* d_in, const int* in_sizes, int n_in,
                              void* d_out, int out_size, void* d_ws, size_t ws_size,
                              hipStream_t stream) {
  (void)in_sizes; (void)n_in; (void)out_size; (void)ws_size;
  const int*   tokens  = (const int*)d_in[0];
  const int*   targets = (const int*)d_in[1];
  const float* embw    = (const float*)d_in[2];
  const float* bnw     = (const float*)d_in[3];
  const float* fc1w    = (const float*)d_in[4];
  const float* fc1b    = (const float*)d_in[5];
  const float* fc2w    = (const float*)d_in[6];
  const float* fc2b    = (const float*)d_in[7];
  const float* nw      = (const float*)d_in[8];
  const float* curw    = (const float*)d_in[9];
  const float* curb    = (const float*)d_in[10];
  const float* nxtw    = (const float*)d_in[11];
  const float* nxtb    = (const float*)d_in[12];
  float* out = (float*)d_out;

  // d_out quadrants (each 8,388,608 floats); all overwritten by final k_logits
  float* cur_all  = out;
  float* s_all    = out + (size_t)NROWS * EE;
  float* inp_all  = out + 2 * (size_t)NROWS * EE;
  float* hbuf_all = out + 3 * (size_t)NROWS * EE;

  float* ws       = (float*)d_ws;
  float* nxt_all  = ws;                       // 8,388,608
  float* ltok     = ws + 8388608;             // 8,192
  float* ltgt     = ws + 8396800;             // 8,192
  unsigned* yh    = (unsigned*)(ws + 8404992);// 65,536 u32
  float* rs_cur   = ws + 8470528;             // 8,192
  float* rs_nxt   = ws + 8478720;             // 8,192
  float* auxac    = ws + 8486912;             // 1 (+pad)
  unsigned* cnt   = (unsigned*)(ws + 8486944);// 1280*17*32 = 696,320
  float* ssS      = ws + 9183264;             // 8,192
  float* ybuf     = ws + 9191456;             // 131,072 (fallback)

  // zero rs_cur..auxac+pad + counters (contiguous span)
  const int nzero = (8486944 + 696320) - 8470528;
  k_zero<<<(nzero + 255) / 256, 256, 0, stream>>>(rs_cur, nzero);
  k_init<<<32, 256, 0, stream>>>(tokens, embw, inp_all);

  Scan4Params p;
  p.tokens = tokens; p.embw = embw; p.bnw = bnw;
  p.fc1w = fc1w; p.fc1b = fc1b; p.fc2w = fc2w; p.fc2b = fc2b;
  p.nw = nw; p.nxtw = nxtw; p.nxtb = nxtb;
  p.inp_all = inp_all; p.s_all = s_all; p.hbuf_all = hbuf_all;
  p.nxt_all = nxt_all; p.yh = yh; p.ssS = ssS; p.cnt = cnt;

  const size_t shmem = 156800;
  hipError_t err = hipFuncSetAttribute((const void*)k_scan4,
      hipFuncAttributeMaxDynamicSharedMemorySize, (int)shmem);
  if (err == hipSuccess) {
    void* args[] = { &p };
    err = hipLaunchCooperativeKernel((const void*)k_scan4, dim3(256), dim3(512),
                                     args, shmem, stream);
  }
  if (err != hipSuccess) {
    // fallback: proven round-1 multi-kernel sequence (fp32)
    float* hbuf = hbuf_all;  // single reused buffer
    for (int t = 0; t < TT; ++t) {
      const float* inp = inp_all + (size_t)t * BE;
      float* s = s_all + (size_t)t * BE;
      k_fc1<<<512, 256, 0, stream>>>(inp, bnw, fc1w, fc1b, ybuf,
                                     hbuf, nullptr, fc2b);
      k_fc2<<<512, 256, 0, stream>>>(ybuf, fc2w, hbuf);
      k_fc1<<<512, 256, 0, stream>>>(hbuf, bnw + EE, fc1w + (size_t)MM * EE,
                                     fc1b + MM, ybuf, s, inp, fc2b + EE);
      k_fc2<<<512, 256, 0, stream>>>(ybuf, fc2w + (size_t)EE * MM, s);
      k_nxt<<<128, 256, 0, stream>>>(s, nw, nxtw, nxtb,
                                     nxt_all + (size_t)t * BE, ssS + t * BB,
                                     tokens, embw,
                                     (t + 1 < TT) ? inp_all + (size_t)(t + 1) * BE : nullptr,
                                     t + 1);
    }
  }

  k_curemb<<<2048, 256, 0, stream>>>(s_all, ssS, nw, curw, curb, inp_all,
                                     cur_all, auxac);
  k_logits<<<8192, 256, 0, stream>>>(cur_all, embw, tokens, rs_cur, ltok, nullptr);
  k_logits<<<8192, 256, 0, stream>>>(nxt_all, embw, targets, rs_nxt, ltgt, out);
  k_final<<<1, 256, 0, stream>>>(rs_cur, rs_nxt, ltok, ltgt, auxac,
                                 out + (size_t)NROWS * VV);
}